// Round 3
// baseline (238.515 us; speedup 1.0000x reference)
//
#include <hip/hip_runtime.h>
#include <hip/hip_bf16.h>

// ---------------- types ----------------
typedef __bf16 bf16x8 __attribute__((ext_vector_type(8)));
typedef __bf16 bf16x4 __attribute__((ext_vector_type(4)));
typedef float  f32x4  __attribute__((ext_vector_type(4)));

__device__ __forceinline__ __bf16 to_bf16(float f) {
    __hip_bfloat16 h = __float2bfloat16(f);
    return *reinterpret_cast<__bf16*>(&h);
}

// DPP 16-lane reductions (full-rate VALU, no LDS/bpermute)
template <int CTRL>
__device__ __forceinline__ float dpp_mov_f(float x) {
    return __builtin_bit_cast(float,
        __builtin_amdgcn_mov_dpp(__builtin_bit_cast(int, x), CTRL, 0xF, 0xF, true));
}
__device__ __forceinline__ float red_max16(float x) {
    x = fmaxf(x, dpp_mov_f<0xB1>(x));   // quad_perm xor1
    x = fmaxf(x, dpp_mov_f<0x4E>(x));   // quad_perm xor2
    x = fmaxf(x, dpp_mov_f<0x141>(x));  // row_half_mirror
    x = fmaxf(x, dpp_mov_f<0x140>(x));  // row_mirror
    return x;
}
__device__ __forceinline__ float red_sum16(float x) {
    x += dpp_mov_f<0xB1>(x);
    x += dpp_mov_f<0x4E>(x);
    x += dpp_mov_f<0x141>(x);
    x += dpp_mov_f<0x140>(x);
    return x;
}

// async global->LDS, 16B per lane; lds ptr must be wave-uniform
__device__ __forceinline__ void gload_lds16(const __bf16* g, __bf16* l) {
    __builtin_amdgcn_global_load_lds(
        (const __attribute__((address_space(1))) void*)g,
        (__attribute__((address_space(3))) void*)l, 16, 0, 0);
}

// constants: B=2, L=2048, DIM=1024, H=16, KVH=4, HD=64, REP=4
// qkv row layout: [0,1024) q heads, [1024,1280) k heads, [1280,1536) v heads

// ---------------- fused prep: 4 weight transposes + x cast, one launch ----------
__global__ __launch_bounds__(256) void prep_k(const float* __restrict__ wq,
                                              const float* __restrict__ wk,
                                              const float* __restrict__ wv,
                                              const float* __restrict__ wo,
                                              const float* __restrict__ x,
                                              __bf16* __restrict__ WqkvT,
                                              __bf16* __restrict__ WoT,
                                              __bf16* __restrict__ xb) {
    int b = blockIdx.x, tid = threadIdx.x;
    if (b >= 2560) {  // x -> bf16 cast, 2048 blocks
        int i = ((b - 2560) * 256 + tid) * 8;
        f32x4 a = *(const f32x4*)(x + i);
        f32x4 c = *(const f32x4*)(x + i + 4);
        bf16x8 h;
        h[0] = to_bf16(a.x); h[1] = to_bf16(a.y); h[2] = to_bf16(a.z); h[3] = to_bf16(a.w);
        h[4] = to_bf16(c.x); h[5] = to_bf16(c.y); h[6] = to_bf16(c.z); h[7] = to_bf16(c.w);
        *(bf16x8*)(xb + i) = h;
        return;
    }
    // weight transpose: src[K=1024][N] f32 -> dst[N][1024] bf16
    __shared__ float tile[32][33];
    const float* src; __bf16* dst; int N, idx;
    if (b < 1024)      { src = wq; dst = WqkvT;                        N = 1024; idx = b; }
    else if (b < 1280) { src = wk; dst = WqkvT + (size_t)1024 * 1024;  N = 256;  idx = b - 1024; }
    else if (b < 1536) { src = wv; dst = WqkvT + (size_t)1280 * 1024;  N = 256;  idx = b - 1280; }
    else               { src = wo; dst = WoT;                          N = 1024; idx = b - 1536; }
    int k0 = (idx & 31) * 32, n0 = (idx >> 5) * 32;
    int tx = tid & 31, ty = tid >> 5;
#pragma unroll
    for (int r = 0; r < 4; ++r) {
        int kk = ty + r * 8;
        tile[kk][tx] = src[(size_t)(k0 + kk) * N + n0 + tx];
    }
    __syncthreads();
#pragma unroll
    for (int r = 0; r < 4; ++r) {
        int nn = ty + r * 8;
        dst[(size_t)(n0 + nn) * 1024 + k0 + tx] = to_bf16(tile[tx][nn]);
    }
}

// ---------------- GEMM (m97-style): A bf16 [M][K], BT bf16 [N][K], C f32 -------
__global__ __launch_bounds__(256) void gemm_bf16_k(const __bf16* __restrict__ A,
                                                   const __bf16* __restrict__ BT,
                                                   float* __restrict__ C,
                                                   int K, int N) {
    __shared__ __bf16 lA[128 * 32];   // unpadded: global_load_lds linear layout
    __shared__ __bf16 lB[128 * 32];
    int tid = threadIdx.x;
    int m0 = blockIdx.x * 128, n0 = blockIdx.y * 128;
    int wid = tid >> 6, lane = tid & 63;
    int wm = (wid >> 1) * 64, wn = (wid & 1) * 64;
    int lm = lane & 15, qd = lane >> 4;

    f32x4 acc[4][4] = {};

    for (int k0 = 0; k0 < K; k0 += 32) {
#pragma unroll
        for (int it = 0; it < 2; ++it) {
            int c = it * 256 + tid;             // 16B chunk id, lane-linear per wave
            int row = c >> 2, c8 = c & 3;
            __bf16* la = lA + (it * 256 + wid * 64) * 8;  // wave-uniform base
            __bf16* lb = lB + (it * 256 + wid * 64) * 8;
            gload_lds16(A  + (size_t)(m0 + row) * K + k0 + c8 * 8, la);
            gload_lds16(BT + (size_t)(n0 + row) * K + k0 + c8 * 8, lb);
        }
        __syncthreads();

        bf16x8 af[4], bfr[4];
#pragma unroll
        for (int t = 0; t < 4; ++t) {
            af[t]  = *(const bf16x8*)&lA[(wm + t * 16 + lm) * 32 + qd * 8];
            bfr[t] = *(const bf16x8*)&lB[(wn + t * 16 + lm) * 32 + qd * 8];
        }
#pragma unroll
        for (int ti = 0; ti < 4; ++ti)
#pragma unroll
            for (int tj = 0; tj < 4; ++tj)
                acc[ti][tj] = __builtin_amdgcn_mfma_f32_16x16x32_bf16(
                    af[ti], bfr[tj], acc[ti][tj], 0, 0, 0);
        __syncthreads();
    }

#pragma unroll
    for (int ti = 0; ti < 4; ++ti)
#pragma unroll
        for (int tj = 0; tj < 4; ++tj)
#pragma unroll
            for (int r = 0; r < 4; ++r) {
                int row = m0 + wm + ti * 16 + qd * 4 + r;
                int col = n0 + wn + tj * 16 + lm;
                C[(size_t)row * N + col] = acc[ti][tj][r];
            }
}

// ---------------- fused RMSNorm+RoPE (q fp32 in-place, k->Kb bf16) + V transpose
__global__ __launch_bounds__(256) void normv_k(float* __restrict__ qkv,
                                               __bf16* __restrict__ Kb,
                                               __bf16* __restrict__ Vt,
                                               const float* __restrict__ gq,
                                               const float* __restrict__ gk) {
    __shared__ float tl[64][65];
    int b = blockIdx.x, tid = threadIdx.x;
    if (b < 20480) {  // norm+rope: wave per (token, head)
        int w = b * 4 + (tid >> 6);
        int lane = tid & 63;
        int t = w / 20, hs = w % 20;
        int pos = t & 2047;
        bool isq = hs < 16;
        int col0 = isq ? hs * 64 : 1024 + (hs - 16) * 64;
        float g = isq ? gq[lane] : gk[lane];
        float* p = qkv + (size_t)t * 1536 + col0;
        float v = p[lane];
        float ss = v * v;
#pragma unroll
        for (int o = 32; o; o >>= 1) ss += __shfl_xor(ss, o);
        float scale = rsqrtf(ss * (1.0f / 64.0f) + 1e-6f);
        v = v * scale * g;
        int i2 = lane >> 1;
        float ex = (float)(2 * i2) * (1.0f / 64.0f);
        float inv = expf(-ex * 9.210340371976184f);
        float ang = (float)pos * inv;
        float c = cosf(ang), s = sinf(ang);
        float pv = __shfl_xor(v, 1);
        float out = (lane & 1) ? (pv * s + v * c) : (v * c - pv * s);
        if (isq) p[lane] = out;
        else Kb[(size_t)t * 256 + (hs - 16) * 64 + lane] = to_bf16(out);
        return;
    }
    // V transpose -> Vt bf16 [(b*4+kvh)*64+d][2048]
    int b2 = b - 20480;
    int g = b2 >> 5, t0 = (b2 & 31) * 64;
    int bb = g >> 2, kvh = g & 3;
    int tx = tid & 63, ty = tid >> 6;
    const float* src = qkv + ((size_t)bb * 2048 + t0) * 1536 + 1280 + kvh * 64;
#pragma unroll
    for (int r = 0; r < 16; ++r) {
        int row = ty * 16 + r;
        tl[row][tx] = src[(size_t)row * 1536 + tx];
    }
    __syncthreads();
#pragma unroll
    for (int r = 0; r < 16; ++r) {
        int d = ty * 16 + r;
        Vt[((size_t)g * 64 + d) * 2048 + t0 + tx] = to_bf16(tl[tx][d]);
    }
}

// ---------------- MFMA flash attention, K-double-buffered, DPP softmax --------
// grid (32, 16, 2). Block = 64 queries of head h; wave = 16 queries, independent.
__global__ __launch_bounds__(256) void attn_k(const float* __restrict__ qkv,
                                              const __bf16* __restrict__ Kb,
                                              const __bf16* __restrict__ Vt,
                                              __bf16* __restrict__ aout) {
    __shared__ __bf16 Pb[4][16][68];   // per-wave P/O transpose buffer (0 conflicts)
    int tid = threadIdx.x, wid = tid >> 6, lane = tid & 63;
    int l15 = lane & 15, quad = lane >> 4;
    int h = blockIdx.y, b = blockIdx.z, kvh = h >> 2;
    int iw = blockIdx.x * 64 + wid * 16;
    size_t tok0 = (size_t)b * 2048;

    // Q A-frags (1/sqrt(64) baked in)
    bf16x8 qf[2];
    {
        const float* qp = qkv + (tok0 + iw + l15) * 1536 + h * 64 + quad * 8;
#pragma unroll
        for (int kh = 0; kh < 2; ++kh) {
            f32x4 u = *(const f32x4*)(qp + kh * 32);
            f32x4 v = *(const f32x4*)(qp + kh * 32 + 4);
            bf16x8 q8;
            q8[0] = to_bf16(u.x * 0.125f); q8[1] = to_bf16(u.y * 0.125f);
            q8[2] = to_bf16(u.z * 0.125f); q8[3] = to_bf16(u.w * 0.125f);
            q8[4] = to_bf16(v.x * 0.125f); q8[5] = to_bf16(v.y * 0.125f);
            q8[6] = to_bf16(v.z * 0.125f); q8[7] = to_bf16(v.w * 0.125f);
            qf[kh] = q8;
        }
    }

    f32x4 o[4] = {};
    float mr[4] = {-INFINITY, -INFINITY, -INFINITY, -INFINITY};
    float lr[4] = {0.f, 0.f, 0.f, 0.f};   // per-lane partial sums (reduced at end)

    int ts = (iw - 256) >> 6; if (ts < 1) ts = 1;
    int tmax = (iw + 15) >> 6;
    int ntl = (tmax >= ts) ? (tmax - ts + 2) : 1;   // [0] + [ts..tmax]

    const __bf16* Kbase = Kb + tok0 * 256 + kvh * 64 + (size_t)l15 * 256 + quad * 8;
    const __bf16* Vbase = Vt + ((size_t)(b * 4 + kvh) * 64 + l15) * 2048 + quad * 8;

    auto loadK = [&](bf16x8* dst, int tt) {
        const __bf16* kp = Kbase + (size_t)tt * 64 * 256;
#pragma unroll
        for (int nt = 0; nt < 4; ++nt) {
            dst[nt * 2]     = *(const bf16x8*)(kp + nt * 16 * 256);
            dst[nt * 2 + 1] = *(const bf16x8*)(kp + nt * 16 * 256 + 32);
        }
    };
    auto loadV = [&](bf16x8* dst, int tt) {
        const __bf16* vp = Vbase + tt * 64;
#pragma unroll
        for (int dt = 0; dt < 4; ++dt) {
            dst[dt * 2]     = *(const bf16x8*)(vp + dt * 16 * 2048);
            dst[dt * 2 + 1] = *(const bf16x8*)(vp + dt * 16 * 2048 + 32);
        }
    };

    bf16x8 kf[2][8];
    loadK(kf[0], 0);   // tile 0 (global keys) always first -> finite m after it

    for (int idx = 0; idx < ntl; ++idx) {
        int tt = (idx == 0) ? 0 : ts + idx - 1;
        bf16x8 vf[8];
        loadV(vf, tt);                                   // lands during QK+softmax
        if (idx + 1 < ntl) loadK(kf[(idx + 1) & 1], ts + idx);  // prefetch next K
        const bf16x8* kc = kf[idx & 1];

        // QK^T: 8 MFMA (C layout: row=quad*4+r, col=nt*16+l15)
        f32x4 s[4] = {};
#pragma unroll
        for (int nt = 0; nt < 4; ++nt) {
            s[nt] = __builtin_amdgcn_mfma_f32_16x16x32_bf16(qf[0], kc[nt * 2],     s[nt], 0, 0, 0);
            s[nt] = __builtin_amdgcn_mfma_f32_16x16x32_bf16(qf[1], kc[nt * 2 + 1], s[nt], 0, 0, 0);
        }

        // mask only where some (i,j) can be invalid (wave-uniform branch)
        bool need_mask = (tt == tmax) || (tt >= 1 && tt * 64 < iw + 15 - 256);
        float p[4][4], alpha[4];
        if (need_mask) {
#pragma unroll
            for (int r = 0; r < 4; ++r) {
                int i = iw + quad * 4 + r;
                f32x4 sv;
#pragma unroll
                for (int nt = 0; nt < 4; ++nt) {
                    int j = tt * 64 + nt * 16 + l15;
                    bool valid = (j <= i) && ((j >= i - 256) || (j < 64));
                    sv[nt] = valid ? s[nt][r] : -INFINITY;
                }
                float mx = red_max16(fmaxf(fmaxf(sv.x, sv.y), fmaxf(sv.z, sv.w)));
                float mn = fmaxf(mr[r], mx);
                alpha[r] = __expf(mr[r] - mn);
                mr[r] = mn;
#pragma unroll
                for (int nt = 0; nt < 4; ++nt) p[nt][r] = __expf(sv[nt] - mn);
                lr[r] = lr[r] * alpha[r] + (p[0][r] + p[1][r] + p[2][r] + p[3][r]);
            }
        } else {
#pragma unroll
            for (int r = 0; r < 4; ++r) {
                float mx = red_max16(fmaxf(fmaxf(s[0][r], s[1][r]), fmaxf(s[2][r], s[3][r])));
                float mn = fmaxf(mr[r], mx);
                alpha[r] = __expf(mr[r] - mn);
                mr[r] = mn;
#pragma unroll
                for (int nt = 0; nt < 4; ++nt) p[nt][r] = __expf(s[nt][r] - mn);
                lr[r] = lr[r] * alpha[r] + (p[0][r] + p[1][r] + p[2][r] + p[3][r]);
            }
        }

        // P: C layout -> A layout via per-wave LDS
#pragma unroll
        for (int nt = 0; nt < 4; ++nt)
#pragma unroll
            for (int r = 0; r < 4; ++r)
                Pb[wid][quad * 4 + r][nt * 16 + l15] = to_bf16(p[nt][r]);
        bf16x8 pf0 = *(const bf16x8*)&Pb[wid][l15][quad * 8];
        bf16x8 pf1 = *(const bf16x8*)&Pb[wid][l15][32 + quad * 8];

        // rescale O, PV: 8 MFMA
#pragma unroll
        for (int dt = 0; dt < 4; ++dt)
#pragma unroll
            for (int r = 0; r < 4; ++r) o[dt][r] *= alpha[r];
#pragma unroll
        for (int dt = 0; dt < 4; ++dt) {
            o[dt] = __builtin_amdgcn_mfma_f32_16x16x32_bf16(pf0, vf[dt * 2],     o[dt], 0, 0, 0);
            o[dt] = __builtin_amdgcn_mfma_f32_16x16x32_bf16(pf1, vf[dt * 2 + 1], o[dt], 0, 0, 0);
        }
    }

    // epilogue: reduce l across 16 lanes, normalize, transpose, coalesced store
    float inv[4];
#pragma unroll
    for (int r = 0; r < 4; ++r) inv[r] = 1.f / red_sum16(lr[r]);
#pragma unroll
    for (int dt = 0; dt < 4; ++dt)
#pragma unroll
        for (int r = 0; r < 4; ++r)
            Pb[wid][quad * 4 + r][dt * 16 + l15] = to_bf16(o[dt][r] * inv[r]);
    __bf16* op = aout + (tok0 + iw + l15) * 1024 + h * 64 + quad * 16;
    bf16x8 o0 = *(const bf16x8*)&Pb[wid][l15][quad * 16];
    bf16x8 o1 = *(const bf16x8*)&Pb[wid][l15][quad * 16 + 8];
    *(bf16x8*)op = o0;
    *(bf16x8*)(op + 8) = o1;
}

// ---------------- launch ----------------
extern "C" void kernel_launch(void* const* d_in, const int* in_sizes, int n_in,
                              void* d_out, int out_size, void* d_ws, size_t ws_size,
                              hipStream_t stream) {
    const float* x  = (const float*)d_in[0];
    const float* wq = (const float*)d_in[1];
    const float* wk = (const float*)d_in[2];
    const float* wv = (const float*)d_in[3];
    const float* wo = (const float*)d_in[4];
    const float* gq = (const float*)d_in[5];
    const float* gk = (const float*)d_in[6];
    float* out = (float*)d_out;

    char* ws = (char*)d_ws;
    float*  qkv   = (float*)ws;                          // 25165824 B
    __bf16* WqkvT = (__bf16*)(ws + 25165824);            //  3145728 B
    __bf16* WoT   = (__bf16*)(ws + 28311552);            //  2097152 B
    __bf16* xb_ao = (__bf16*)(ws + 30408704);            //  8388608 B (xb, then aout)
    __bf16* Kb    = (__bf16*)(ws + 38797312);            //  2097152 B
    __bf16* Vt    = (__bf16*)(ws + 40894464);            //  2097152 B

    dim3 tb(256);
    prep_k<<<4608, tb, 0, stream>>>(wq, wk, wv, wo, x, WqkvT, WoT, xb_ao);
    gemm_bf16_k<<<dim3(32, 12), tb, 0, stream>>>(xb_ao, WqkvT, qkv, 1024, 1536);
    normv_k<<<20736, tb, 0, stream>>>(qkv, Kb, Vt, gq, gk);
    attn_k<<<dim3(32, 16, 2), tb, 0, stream>>>(qkv, Kb, Vt, xb_ao);   // aout reuses xb
    gemm_bf16_k<<<dim3(32, 8), tb, 0, stream>>>(xb_ao, WoT, out, 1024, 1024);
}

// Round 4
// 229.519 us; speedup vs baseline: 1.0392x; 1.0392x over previous
//
#include <hip/hip_runtime.h>
#include <hip/hip_bf16.h>

// ---------------- types ----------------
typedef __bf16 bf16x8 __attribute__((ext_vector_type(8)));
typedef __bf16 bf16x4 __attribute__((ext_vector_type(4)));
typedef float  f32x4  __attribute__((ext_vector_type(4)));
typedef short  s16x4  __attribute__((ext_vector_type(4)));

__device__ __forceinline__ __bf16 to_bf16(float f) {
    __hip_bfloat16 h = __float2bfloat16(f);
    return *reinterpret_cast<__bf16*>(&h);
}

// 16x16x16 bf16 MFMA: new-style builtin if present, else gfx90a-era _1k spelling
__device__ __forceinline__ f32x4 mfma16(bf16x4 a, bf16x4 b, f32x4 c) {
#if __has_builtin(__builtin_amdgcn_mfma_f32_16x16x16_bf16)
    return __builtin_amdgcn_mfma_f32_16x16x16_bf16(a, b, c, 0, 0, 0);
#else
    return __builtin_amdgcn_mfma_f32_16x16x16bf16_1k(
        __builtin_bit_cast(s16x4, a), __builtin_bit_cast(s16x4, b), c, 0, 0, 0);
#endif
}

// async global->LDS, 16B per lane; lds ptr must be wave-uniform
__device__ __forceinline__ void gload_lds16(const __bf16* g, __bf16* l) {
    __builtin_amdgcn_global_load_lds(
        (const __attribute__((address_space(1))) void*)g,
        (__attribute__((address_space(3))) void*)l, 16, 0, 0);
}

// constants: B=2, L=2048, DIM=1024, H=16, KVH=4, HD=64, REP=4
// qkv row layout: [0,1024) q heads, [1024,1280) k heads, [1280,1536) v heads

// ---------------- fused prep: 4 weight transposes + x cast, one launch ----------
__global__ __launch_bounds__(256) void prep_k(const float* __restrict__ wq,
                                              const float* __restrict__ wk,
                                              const float* __restrict__ wv,
                                              const float* __restrict__ wo,
                                              const float* __restrict__ x,
                                              __bf16* __restrict__ WqkvT,
                                              __bf16* __restrict__ WoT,
                                              __bf16* __restrict__ xb) {
    int b = blockIdx.x, tid = threadIdx.x;
    if (b >= 2560) {  // x -> bf16 cast, 2048 blocks
        int i = ((b - 2560) * 256 + tid) * 8;
        f32x4 a = *(const f32x4*)(x + i);
        f32x4 c = *(const f32x4*)(x + i + 4);
        bf16x8 h;
        h[0] = to_bf16(a.x); h[1] = to_bf16(a.y); h[2] = to_bf16(a.z); h[3] = to_bf16(a.w);
        h[4] = to_bf16(c.x); h[5] = to_bf16(c.y); h[6] = to_bf16(c.z); h[7] = to_bf16(c.w);
        *(bf16x8*)(xb + i) = h;
        return;
    }
    __shared__ float tile[32][33];
    const float* src; __bf16* dst; int N, idx;
    if (b < 1024)      { src = wq; dst = WqkvT;                        N = 1024; idx = b; }
    else if (b < 1280) { src = wk; dst = WqkvT + (size_t)1024 * 1024;  N = 256;  idx = b - 1024; }
    else if (b < 1536) { src = wv; dst = WqkvT + (size_t)1280 * 1024;  N = 256;  idx = b - 1280; }
    else               { src = wo; dst = WoT;                          N = 1024; idx = b - 1536; }
    int k0 = (idx & 31) * 32, n0 = (idx >> 5) * 32;
    int tx = tid & 31, ty = tid >> 5;
#pragma unroll
    for (int r = 0; r < 4; ++r) {
        int kk = ty + r * 8;
        tile[kk][tx] = src[(size_t)(k0 + kk) * N + n0 + tx];
    }
    __syncthreads();
#pragma unroll
    for (int r = 0; r < 4; ++r) {
        int nn = ty + r * 8;
        dst[(size_t)(n0 + nn) * 1024 + k0 + tx] = to_bf16(tile[tx][nn]);
    }
}

// ---------------- GEMM (m97-style): A bf16 [M][K], BT bf16 [N][K], C f32 -------
__global__ __launch_bounds__(256) void gemm_bf16_k(const __bf16* __restrict__ A,
                                                   const __bf16* __restrict__ BT,
                                                   float* __restrict__ C,
                                                   int K, int N) {
    __shared__ __bf16 lA[128 * 32];
    __shared__ __bf16 lB[128 * 32];
    int tid = threadIdx.x;
    int m0 = blockIdx.x * 128, n0 = blockIdx.y * 128;
    int wid = tid >> 6, lane = tid & 63;
    int wm = (wid >> 1) * 64, wn = (wid & 1) * 64;
    int lm = lane & 15, qd = lane >> 4;

    f32x4 acc[4][4] = {};

    for (int k0 = 0; k0 < K; k0 += 32) {
#pragma unroll
        for (int it = 0; it < 2; ++it) {
            int c = it * 256 + tid;
            int row = c >> 2, c8 = c & 3;
            __bf16* la = lA + (it * 256 + wid * 64) * 8;
            __bf16* lb = lB + (it * 256 + wid * 64) * 8;
            gload_lds16(A  + (size_t)(m0 + row) * K + k0 + c8 * 8, la);
            gload_lds16(BT + (size_t)(n0 + row) * K + k0 + c8 * 8, lb);
        }
        __syncthreads();

        bf16x8 af[4], bfr[4];
#pragma unroll
        for (int t = 0; t < 4; ++t) {
            af[t]  = *(const bf16x8*)&lA[(wm + t * 16 + lm) * 32 + qd * 8];
            bfr[t] = *(const bf16x8*)&lB[(wn + t * 16 + lm) * 32 + qd * 8];
        }
#pragma unroll
        for (int ti = 0; ti < 4; ++ti)
#pragma unroll
            for (int tj = 0; tj < 4; ++tj)
                acc[ti][tj] = __builtin_amdgcn_mfma_f32_16x16x32_bf16(
                    af[ti], bfr[tj], acc[ti][tj], 0, 0, 0);
        __syncthreads();
    }

#pragma unroll
    for (int ti = 0; ti < 4; ++ti)
#pragma unroll
        for (int tj = 0; tj < 4; ++tj)
#pragma unroll
            for (int r = 0; r < 4; ++r) {
                int row = m0 + wm + ti * 16 + qd * 4 + r;
                int col = n0 + wn + tj * 16 + lm;
                C[(size_t)row * N + col] = acc[ti][tj][r];
            }
}

// ---------------- fused RMSNorm+RoPE (q fp32 in-place, k->Kb bf16) + V transpose
__global__ __launch_bounds__(256) void normv_k(float* __restrict__ qkv,
                                               __bf16* __restrict__ Kb,
                                               __bf16* __restrict__ Vt,
                                               const float* __restrict__ gq,
                                               const float* __restrict__ gk) {
    __shared__ float tl[64][65];
    int b = blockIdx.x, tid = threadIdx.x;
    if (b < 20480) {
        int w = b * 4 + (tid >> 6);
        int lane = tid & 63;
        int t = w / 20, hs = w % 20;
        int pos = t & 2047;
        bool isq = hs < 16;
        int col0 = isq ? hs * 64 : 1024 + (hs - 16) * 64;
        float g = isq ? gq[lane] : gk[lane];
        float* p = qkv + (size_t)t * 1536 + col0;
        float v = p[lane];
        float ss = v * v;
#pragma unroll
        for (int o = 32; o; o >>= 1) ss += __shfl_xor(ss, o);
        float scale = rsqrtf(ss * (1.0f / 64.0f) + 1e-6f);
        v = v * scale * g;
        int i2 = lane >> 1;
        float ex = (float)(2 * i2) * (1.0f / 64.0f);
        float inv = expf(-ex * 9.210340371976184f);
        float ang = (float)pos * inv;
        float c = cosf(ang), s = sinf(ang);
        float pv = __shfl_xor(v, 1);
        float out = (lane & 1) ? (pv * s + v * c) : (v * c - pv * s);
        if (isq) p[lane] = out;
        else Kb[(size_t)t * 256 + (hs - 16) * 64 + lane] = to_bf16(out);
        return;
    }
    int b2 = b - 20480;
    int g = b2 >> 5, t0 = (b2 & 31) * 64;
    int bb = g >> 2, kvh = g & 3;
    int tx = tid & 63, ty = tid >> 6;
    const float* src = qkv + ((size_t)bb * 2048 + t0) * 1536 + 1280 + kvh * 64;
#pragma unroll
    for (int r = 0; r < 16; ++r) {
        int row = ty * 16 + r;
        tl[row][tx] = src[(size_t)row * 1536 + tx];
    }
    __syncthreads();
#pragma unroll
    for (int r = 0; r < 16; ++r) {
        int d = ty * 16 + r;
        Vt[((size_t)g * 64 + d) * 2048 + t0 + tx] = to_bf16(tl[tx][d]);
    }
}

// ---------------- MFMA flash attention, S^T form, 4-way KV split --------------
// grid (128, 16, 2). Block = (b, h, 16 queries). Wave w handles tile indices
// w, w+4, ... of the list [0] ++ [ts..tmax]; partials merged via LDS.
// S^T = K.Q^T  (A=K-frag, B=Q-frag); P^T in C-layout feeds 16x16x16 PV directly
// as B (C-layout == B-layout identity) with A = V^T from Vt. No per-tile LDS.
__global__ __launch_bounds__(256) void attn_k(const float* __restrict__ qkv,
                                              const __bf16* __restrict__ Kb,
                                              const __bf16* __restrict__ Vt,
                                              __bf16* __restrict__ aout) {
    __shared__ float Ow[4][64][17];   // [wave][dim][query], +1 pad
    __shared__ float Ml[4][16];       // per-wave running max (per query)
    __shared__ float Ll[4][4][16];    // per-wave per-quad l partials
    int tid = threadIdx.x, wid = tid >> 6, lane = tid & 63;
    int l15 = lane & 15, quad = lane >> 4;
    int h = blockIdx.y, b = blockIdx.z, kvh = h >> 2;
    int iw = blockIdx.x * 16;
    size_t tok0 = (size_t)b * 2048;

    // Q^T B-frags (lane: n=query=l15, k=dim=quad*8+j), 1/8 baked in
    bf16x8 qf[2];
    {
        const float* qp = qkv + (tok0 + iw + l15) * 1536 + h * 64 + quad * 8;
#pragma unroll
        for (int kh = 0; kh < 2; ++kh) {
            f32x4 u = *(const f32x4*)(qp + kh * 32);
            f32x4 v = *(const f32x4*)(qp + kh * 32 + 4);
            bf16x8 q8;
            q8[0] = to_bf16(u.x * 0.125f); q8[1] = to_bf16(u.y * 0.125f);
            q8[2] = to_bf16(u.z * 0.125f); q8[3] = to_bf16(u.w * 0.125f);
            q8[4] = to_bf16(v.x * 0.125f); q8[5] = to_bf16(v.y * 0.125f);
            q8[6] = to_bf16(v.z * 0.125f); q8[7] = to_bf16(v.w * 0.125f);
            qf[kh] = q8;
        }
    }

    f32x4 o[4] = {};                 // O^T[dim=dt*16+quad*4+r][query=l15]
    float mr = -1e30f, lrp = 0.f;    // finite sentinel: empty partials stay safe

    int ts = (iw - 256) >> 6; if (ts < 1) ts = 1;
    int tmax = (iw + 15) >> 6;
    int nwin = (tmax >= ts) ? (tmax - ts + 1) : 0;
    int n_all = 1 + nwin;

    const __bf16* Kbase = Kb + tok0 * 256 + kvh * 64 + (size_t)l15 * 256 + quad * 8;
    const __bf16* Vbase = Vt + ((size_t)(b * 4 + kvh) * 64 + l15) * 2048 + quad * 4;
    int iq = iw + l15;               // this lane's query index

    for (int ti = wid; ti < n_all; ti += 4) {
        int tt = (ti == 0) ? 0 : ts + ti - 1;

        // QK^T: S^T frags (C layout: row=key piece=quad*4+r, col=query=l15)
        f32x4 s[4] = {};
        const __bf16* kp0 = Kbase + (size_t)tt * 64 * 256;
#pragma unroll
        for (int nt = 0; nt < 4; ++nt) {
            const __bf16* kp = kp0 + nt * 16 * 256;
            s[nt] = __builtin_amdgcn_mfma_f32_16x16x32_bf16(
                *(const bf16x8*)kp, qf[0], s[nt], 0, 0, 0);
            s[nt] = __builtin_amdgcn_mfma_f32_16x16x32_bf16(
                *(const bf16x8*)(kp + 32), qf[1], s[nt], 0, 0, 0);
        }

        // mask + in-lane max + cross-quad max
        float mx = -1e30f;
#pragma unroll
        for (int nt = 0; nt < 4; ++nt)
#pragma unroll
            for (int r = 0; r < 4; ++r) {
                int j = tt * 64 + nt * 16 + quad * 4 + r;
                bool valid = (j <= iq) && ((j >= iq - 256) || (j < 64));
                float xv = valid ? s[nt][r] : -1e30f;
                s[nt][r] = xv;
                mx = fmaxf(mx, xv);
            }
        mx = fmaxf(mx, __shfl_xor(mx, 16));
        mx = fmaxf(mx, __shfl_xor(mx, 32));
        float mn = fmaxf(mr, mx);
        float alpha = __expf(mr - mn);
        mr = mn;

        float ps = 0.f;
        bf16x4 pb[4];
#pragma unroll
        for (int nt = 0; nt < 4; ++nt)
#pragma unroll
            for (int r = 0; r < 4; ++r) {
                float pv = __expf(s[nt][r] - mn);
                ps += pv;
                pb[nt][r] = to_bf16(pv);
            }
        lrp = lrp * alpha + ps;

        // rescale O^T (alpha is per-query = per-lane scalar), then PV
#pragma unroll
        for (int dt = 0; dt < 4; ++dt) o[dt] *= alpha;
        const __bf16* vp0 = Vbase + tt * 64;
#pragma unroll
        for (int dt = 0; dt < 4; ++dt) {
            const __bf16* vp = vp0 + (size_t)dt * 16 * 2048;
#pragma unroll
            for (int nt = 0; nt < 4; ++nt)
                o[dt] = mfma16(*(const bf16x4*)(vp + nt * 16), pb[nt], o[dt]);
        }
    }

    // write partials
#pragma unroll
    for (int dt = 0; dt < 4; ++dt)
#pragma unroll
        for (int r = 0; r < 4; ++r)
            Ow[wid][dt * 16 + quad * 4 + r][l15] = o[dt][r];
    Ml[wid][l15] = mr;              // identical across quads
    Ll[wid][quad][l15] = lrp;
    __syncthreads();

    // combine: thread = (query qy = tid>>4, dim group dg = tid&15)
    int qy = tid >> 4, dg = tid & 15;
    float M = fmaxf(fmaxf(Ml[0][qy], Ml[1][qy]), fmaxf(Ml[2][qy], Ml[3][qy]));
    float lsum = 0.f;
    float acc[4] = {0.f, 0.f, 0.f, 0.f};
#pragma unroll
    for (int w = 0; w < 4; ++w) {
        float aw = __expf(Ml[w][qy] - M);
        lsum += aw * (Ll[w][0][qy] + Ll[w][1][qy] + Ll[w][2][qy] + Ll[w][3][qy]);
#pragma unroll
        for (int d = 0; d < 4; ++d) acc[d] += aw * Ow[w][dg * 4 + d][qy];
    }
    float inv = 1.f / lsum;
    bf16x4 r4;
#pragma unroll
    for (int d = 0; d < 4; ++d) r4[d] = to_bf16(acc[d] * inv);
    *(bf16x4*)(aout + (tok0 + iw + qy) * 1024 + h * 64 + dg * 4) = r4;
}

// ---------------- launch ----------------
extern "C" void kernel_launch(void* const* d_in, const int* in_sizes, int n_in,
                              void* d_out, int out_size, void* d_ws, size_t ws_size,
                              hipStream_t stream) {
    const float* x  = (const float*)d_in[0];
    const float* wq = (const float*)d_in[1];
    const float* wk = (const float*)d_in[2];
    const float* wv = (const float*)d_in[3];
    const float* wo = (const float*)d_in[4];
    const float* gq = (const float*)d_in[5];
    const float* gk = (const float*)d_in[6];
    float* out = (float*)d_out;

    char* ws = (char*)d_ws;
    float*  qkv   = (float*)ws;                          // 25165824 B
    __bf16* WqkvT = (__bf16*)(ws + 25165824);            //  3145728 B
    __bf16* WoT   = (__bf16*)(ws + 28311552);            //  2097152 B
    __bf16* xb_ao = (__bf16*)(ws + 30408704);            //  8388608 B (xb, then aout)
    __bf16* Kb    = (__bf16*)(ws + 38797312);            //  2097152 B
    __bf16* Vt    = (__bf16*)(ws + 40894464);            //  2097152 B

    dim3 tb(256);
    prep_k<<<4608, tb, 0, stream>>>(wq, wk, wv, wo, x, WqkvT, WoT, xb_ao);
    gemm_bf16_k<<<dim3(32, 12), tb, 0, stream>>>(xb_ao, WqkvT, qkv, 1024, 1536);
    normv_k<<<20736, tb, 0, stream>>>(qkv, Kb, Vt, gq, gk);
    attn_k<<<dim3(128, 16, 2), tb, 0, stream>>>(qkv, Kb, Vt, xb_ao);  // aout reuses xb
    gemm_bf16_k<<<dim3(32, 8), tb, 0, stream>>>(xb_ao, WoT, out, 1024, 1024);
}

// Round 5
// 226.467 us; speedup vs baseline: 1.0532x; 1.0135x over previous
//
#include <hip/hip_runtime.h>
#include <hip/hip_bf16.h>

// ---------------- types ----------------
typedef __bf16 bf16x8 __attribute__((ext_vector_type(8)));
typedef __bf16 bf16x4 __attribute__((ext_vector_type(4)));
typedef float  f32x4  __attribute__((ext_vector_type(4)));
typedef short  s16x4  __attribute__((ext_vector_type(4)));

__device__ __forceinline__ __bf16 to_bf16(float f) {
    __hip_bfloat16 h = __float2bfloat16(f);
    return *reinterpret_cast<__bf16*>(&h);
}

// 16x16x16 bf16 MFMA (PV): C-layout of QK == B-layout here, so P^T feeds directly
__device__ __forceinline__ f32x4 mfma16(bf16x4 a, bf16x4 b, f32x4 c) {
#if __has_builtin(__builtin_amdgcn_mfma_f32_16x16x16_bf16)
    return __builtin_amdgcn_mfma_f32_16x16x16_bf16(a, b, c, 0, 0, 0);
#else
    return __builtin_amdgcn_mfma_f32_16x16x16bf16_1k(
        __builtin_bit_cast(s16x4, a), __builtin_bit_cast(s16x4, b), c, 0, 0, 0);
#endif
}

// async global->LDS, 16B per lane; lds ptr must be wave-uniform
__device__ __forceinline__ void gload_lds16(const __bf16* g, __bf16* l) {
    __builtin_amdgcn_global_load_lds(
        (const __attribute__((address_space(1))) void*)g,
        (__attribute__((address_space(3))) void*)l, 16, 0, 0);
}

// constants: B=2, L=2048, DIM=1024, H=16, KVH=4, HD=64, REP=4
// qkv row layout: [0,1024) q heads, [1024,1280) k heads, [1280,1536) v heads

// ---------------- fused prep: 4 weight transposes + x cast, one launch ----------
__global__ __launch_bounds__(256) void prep_k(const float* __restrict__ wq,
                                              const float* __restrict__ wk,
                                              const float* __restrict__ wv,
                                              const float* __restrict__ wo,
                                              const float* __restrict__ x,
                                              __bf16* __restrict__ WqkvT,
                                              __bf16* __restrict__ WoT,
                                              __bf16* __restrict__ xb) {
    int b = blockIdx.x, tid = threadIdx.x;
    if (b >= 2560) {  // x -> bf16 cast, 2048 blocks
        int i = ((b - 2560) * 256 + tid) * 8;
        f32x4 a = *(const f32x4*)(x + i);
        f32x4 c = *(const f32x4*)(x + i + 4);
        bf16x8 h;
        h[0] = to_bf16(a.x); h[1] = to_bf16(a.y); h[2] = to_bf16(a.z); h[3] = to_bf16(a.w);
        h[4] = to_bf16(c.x); h[5] = to_bf16(c.y); h[6] = to_bf16(c.z); h[7] = to_bf16(c.w);
        *(bf16x8*)(xb + i) = h;
        return;
    }
    __shared__ float tile[32][33];
    const float* src; __bf16* dst; int N, idx;
    if (b < 1024)      { src = wq; dst = WqkvT;                        N = 1024; idx = b; }
    else if (b < 1280) { src = wk; dst = WqkvT + (size_t)1024 * 1024;  N = 256;  idx = b - 1024; }
    else if (b < 1536) { src = wv; dst = WqkvT + (size_t)1280 * 1024;  N = 256;  idx = b - 1280; }
    else               { src = wo; dst = WoT;                          N = 1024; idx = b - 1536; }
    int k0 = (idx & 31) * 32, n0 = (idx >> 5) * 32;
    int tx = tid & 31, ty = tid >> 5;
#pragma unroll
    for (int r = 0; r < 4; ++r) {
        int kk = ty + r * 8;
        tile[kk][tx] = src[(size_t)(k0 + kk) * N + n0 + tx];
    }
    __syncthreads();
#pragma unroll
    for (int r = 0; r < 4; ++r) {
        int nn = ty + r * 8;
        dst[(size_t)(n0 + nn) * 1024 + k0 + tx] = to_bf16(tile[tx][nn]);
    }
}

// ---------------- GEMM (m97-style): A bf16 [M][K], BT bf16 [N][K], C f32 -------
__global__ __launch_bounds__(256) void gemm_bf16_k(const __bf16* __restrict__ A,
                                                   const __bf16* __restrict__ BT,
                                                   float* __restrict__ C,
                                                   int K, int N) {
    __shared__ __bf16 lA[128 * 32];
    __shared__ __bf16 lB[128 * 32];
    int tid = threadIdx.x;
    int m0 = blockIdx.x * 128, n0 = blockIdx.y * 128;
    int wid = tid >> 6, lane = tid & 63;
    int wm = (wid >> 1) * 64, wn = (wid & 1) * 64;
    int lm = lane & 15, qd = lane >> 4;

    f32x4 acc[4][4] = {};

    for (int k0 = 0; k0 < K; k0 += 32) {
#pragma unroll
        for (int it = 0; it < 2; ++it) {
            int c = it * 256 + tid;
            int row = c >> 2, c8 = c & 3;
            __bf16* la = lA + (it * 256 + wid * 64) * 8;
            __bf16* lb = lB + (it * 256 + wid * 64) * 8;
            gload_lds16(A  + (size_t)(m0 + row) * K + k0 + c8 * 8, la);
            gload_lds16(BT + (size_t)(n0 + row) * K + k0 + c8 * 8, lb);
        }
        __syncthreads();

        bf16x8 af[4], bfr[4];
#pragma unroll
        for (int t = 0; t < 4; ++t) {
            af[t]  = *(const bf16x8*)&lA[(wm + t * 16 + lm) * 32 + qd * 8];
            bfr[t] = *(const bf16x8*)&lB[(wn + t * 16 + lm) * 32 + qd * 8];
        }
#pragma unroll
        for (int ti = 0; ti < 4; ++ti)
#pragma unroll
            for (int tj = 0; tj < 4; ++tj)
                acc[ti][tj] = __builtin_amdgcn_mfma_f32_16x16x32_bf16(
                    af[ti], bfr[tj], acc[ti][tj], 0, 0, 0);
        __syncthreads();
    }

#pragma unroll
    for (int ti = 0; ti < 4; ++ti)
#pragma unroll
        for (int tj = 0; tj < 4; ++tj)
#pragma unroll
            for (int r = 0; r < 4; ++r) {
                int row = m0 + wm + ti * 16 + qd * 4 + r;
                int col = n0 + wn + tj * 16 + lm;
                C[(size_t)row * N + col] = acc[ti][tj][r];
            }
}

// ---------------- fused RMSNorm+RoPE (q fp32 in-place, k->Kb bf16) + V transpose
__global__ __launch_bounds__(256) void normv_k(float* __restrict__ qkv,
                                               __bf16* __restrict__ Kb,
                                               __bf16* __restrict__ Vt,
                                               const float* __restrict__ gq,
                                               const float* __restrict__ gk) {
    __shared__ float tl[64][65];
    int b = blockIdx.x, tid = threadIdx.x;
    if (b < 20480) {
        int w = b * 4 + (tid >> 6);
        int lane = tid & 63;
        int t = w / 20, hs = w % 20;
        int pos = t & 2047;
        bool isq = hs < 16;
        int col0 = isq ? hs * 64 : 1024 + (hs - 16) * 64;
        float g = isq ? gq[lane] : gk[lane];
        float* p = qkv + (size_t)t * 1536 + col0;
        float v = p[lane];
        float ss = v * v;
#pragma unroll
        for (int o = 32; o; o >>= 1) ss += __shfl_xor(ss, o);
        float scale = rsqrtf(ss * (1.0f / 64.0f) + 1e-6f);
        v = v * scale * g;
        int i2 = lane >> 1;
        float ex = (float)(2 * i2) * (1.0f / 64.0f);
        float inv = expf(-ex * 9.210340371976184f);
        float ang = (float)pos * inv;
        float c = cosf(ang), s = sinf(ang);
        float pv = __shfl_xor(v, 1);
        float out = (lane & 1) ? (pv * s + v * c) : (v * c - pv * s);
        if (isq) p[lane] = out;
        else Kb[(size_t)t * 256 + (hs - 16) * 64 + lane] = to_bf16(out);
        return;
    }
    int b2 = b - 20480;
    int g = b2 >> 5, t0 = (b2 & 31) * 64;
    int bb = g >> 2, kvh = g & 3;
    int tx = tid & 63, ty = tid >> 6;
    const float* src = qkv + ((size_t)bb * 2048 + t0) * 1536 + 1280 + kvh * 64;
#pragma unroll
    for (int r = 0; r < 16; ++r) {
        int row = ty * 16 + r;
        tl[row][tx] = src[(size_t)row * 1536 + tx];
    }
    __syncthreads();
#pragma unroll
    for (int r = 0; r < 16; ++r) {
        int d = ty * 16 + r;
        Vt[((size_t)g * 64 + d) * 2048 + t0 + tx] = to_bf16(tl[tx][d]);
    }
}

// ---------------- MFMA flash attention, S^T form, wave-serial + K prefetch ----
// grid (128, 16, 2), block = 64 threads = ONE wave = 16 queries of head h.
// Tile list: [0] ++ [ts..tmax]. K frags double-buffered via explicit register
// rotation (constant indices only -- NO dynamic indexing, it demotes to scratch).
__global__ __launch_bounds__(64) void attn_k(const float* __restrict__ qkv,
                                             const __bf16* __restrict__ Kb,
                                             const __bf16* __restrict__ Vt,
                                             __bf16* __restrict__ aout) {
    __shared__ __bf16 Pb[16][80];     // epilogue transpose only (rows 16B-aligned)
    int lane = threadIdx.x;
    int l15 = lane & 15, quad = lane >> 4;
    int h = blockIdx.y, b = blockIdx.z, kvh = h >> 2;
    int iw = blockIdx.x * 16;
    size_t tok0 = (size_t)b * 2048;

    // Q^T B-frag (lane: n=query=l15, k=dim=quad*8+j), 1/sqrt(64) baked in
    bf16x8 qf0, qf1;
    {
        const float* qp = qkv + (tok0 + iw + l15) * 1536 + h * 64 + quad * 8;
        f32x4 u0 = *(const f32x4*)(qp);
        f32x4 v0 = *(const f32x4*)(qp + 4);
        f32x4 u1 = *(const f32x4*)(qp + 32);
        f32x4 v1 = *(const f32x4*)(qp + 36);
        qf0[0] = to_bf16(u0.x * 0.125f); qf0[1] = to_bf16(u0.y * 0.125f);
        qf0[2] = to_bf16(u0.z * 0.125f); qf0[3] = to_bf16(u0.w * 0.125f);
        qf0[4] = to_bf16(v0.x * 0.125f); qf0[5] = to_bf16(v0.y * 0.125f);
        qf0[6] = to_bf16(v0.z * 0.125f); qf0[7] = to_bf16(v0.w * 0.125f);
        qf1[0] = to_bf16(u1.x * 0.125f); qf1[1] = to_bf16(u1.y * 0.125f);
        qf1[2] = to_bf16(u1.z * 0.125f); qf1[3] = to_bf16(u1.w * 0.125f);
        qf1[4] = to_bf16(v1.x * 0.125f); qf1[5] = to_bf16(v1.y * 0.125f);
        qf1[6] = to_bf16(v1.z * 0.125f); qf1[7] = to_bf16(v1.w * 0.125f);
    }

    f32x4 o[4] = {};                 // O^T[dim=dt*16+quad*4+r][query=l15]
    float mr = -1e30f, lrp = 0.f;    // per-lane; l reduced across quads at end

    int ts = (iw - 256) >> 6; if (ts < 1) ts = 1;
    int tmax = (iw + 15) >> 6;
    int nwin = (tmax >= ts) ? (tmax - ts + 1) : 0;
    int n_all = 1 + nwin;

    const __bf16* Kbase = Kb + tok0 * 256 + kvh * 64 + (size_t)l15 * 256 + quad * 8;
    const __bf16* Vbase = Vt + ((size_t)(b * 4 + kvh) * 64 + l15) * 2048 + quad * 4;
    int iq = iw + l15;

    auto loadK = [&](bf16x8* d, int tt) {
        const __bf16* kp = Kbase + (size_t)tt * 64 * 256;
#pragma unroll
        for (int nt = 0; nt < 4; ++nt) {
            d[nt * 2]     = *(const bf16x8*)(kp + nt * 16 * 256);
            d[nt * 2 + 1] = *(const bf16x8*)(kp + nt * 16 * 256 + 32);
        }
    };

    bf16x8 kc[8], kn[8];
    loadK(kc, 0);                       // tile 0 (global keys) first

    for (int idx = 0; idx < n_all; ++idx) {
        int tt = (idx == 0) ? 0 : ts + idx - 1;
        int ttn = ts + idx; if (ttn > tmax) ttn = tmax;   // clamped prefetch
        loadK(kn, ttn);                                   // next-K in flight

        // V loads issued early; land during QK + softmax
        bf16x4 vf[16];
        const __bf16* vp0 = Vbase + tt * 64;
#pragma unroll
        for (int dt = 0; dt < 4; ++dt)
#pragma unroll
            for (int nt = 0; nt < 4; ++nt)
                vf[dt * 4 + nt] = *(const bf16x4*)(vp0 + (size_t)dt * 16 * 2048 + nt * 16);

        // QK^T: S^T (C layout: row=key=nt*16+quad*4+r, col=query=l15)
        f32x4 s[4] = {};
#pragma unroll
        for (int nt = 0; nt < 4; ++nt) {
            s[nt] = __builtin_amdgcn_mfma_f32_16x16x32_bf16(kc[nt * 2],     qf0, s[nt], 0, 0, 0);
            s[nt] = __builtin_amdgcn_mfma_f32_16x16x32_bf16(kc[nt * 2 + 1], qf1, s[nt], 0, 0, 0);
        }

        // mask (only where some (i,j) can be invalid; wave-uniform branch)
        bool need_mask = (tt == tmax) || (tt >= 1 && tt * 64 < iw + 15 - 256);
        if (need_mask) {
#pragma unroll
            for (int nt = 0; nt < 4; ++nt)
#pragma unroll
                for (int r = 0; r < 4; ++r) {
                    int j = tt * 64 + nt * 16 + quad * 4 + r;
                    bool valid = (j <= iq) && ((j >= iq - 256) || (j < 64));
                    s[nt][r] = valid ? s[nt][r] : -1e30f;
                }
        }

        // online softmax: in-lane max over 16 keys + cross-quad reduce
        float mx = -1e30f;
#pragma unroll
        for (int nt = 0; nt < 4; ++nt)
#pragma unroll
            for (int r = 0; r < 4; ++r) mx = fmaxf(mx, s[nt][r]);
        mx = fmaxf(mx, __shfl_xor(mx, 16));
        mx = fmaxf(mx, __shfl_xor(mx, 32));
        float mn = fmaxf(mr, mx);
        float alpha = __expf(mr - mn);
        mr = mn;

        float ps = 0.f;
        bf16x4 pb[4];
#pragma unroll
        for (int nt = 0; nt < 4; ++nt)
#pragma unroll
            for (int r = 0; r < 4; ++r) {
                float pv = __expf(s[nt][r] - mn);
                ps += pv;
                pb[nt][r] = to_bf16(pv);
            }
        lrp = lrp * alpha + ps;

        // rescale O^T (per-lane scalar), PV with A=V^T, B=P^T (register-direct)
#pragma unroll
        for (int dt = 0; dt < 4; ++dt) {
            o[dt] *= alpha;
#pragma unroll
            for (int nt = 0; nt < 4; ++nt)
                o[dt] = mfma16(vf[dt * 4 + nt], pb[nt], o[dt]);
        }

        // rotate K buffers (constant-index copies -> stays in VGPRs)
#pragma unroll
        for (int r = 0; r < 8; ++r) kc[r] = kn[r];
    }

    // l: sum across quads; normalize; transpose via LDS; coalesced 16B stores
    lrp += __shfl_xor(lrp, 16);
    lrp += __shfl_xor(lrp, 32);
    float inv = 1.f / lrp;
#pragma unroll
    for (int dt = 0; dt < 4; ++dt)
#pragma unroll
        for (int r = 0; r < 4; ++r)
            Pb[l15][dt * 16 + quad * 4 + r] = to_bf16(o[dt][r] * inv);
    // single wave: compiler orders ds_write -> ds_read with waitcnt
    bf16x8 o0 = *(const bf16x8*)&Pb[l15][quad * 16];
    bf16x8 o1 = *(const bf16x8*)&Pb[l15][quad * 16 + 8];
    __bf16* op = aout + (tok0 + iw + l15) * 1024 + h * 64 + quad * 16;
    *(bf16x8*)op = o0;
    *(bf16x8*)(op + 8) = o1;
}

// ---------------- launch ----------------
extern "C" void kernel_launch(void* const* d_in, const int* in_sizes, int n_in,
                              void* d_out, int out_size, void* d_ws, size_t ws_size,
                              hipStream_t stream) {
    const float* x  = (const float*)d_in[0];
    const float* wq = (const float*)d_in[1];
    const float* wk = (const float*)d_in[2];
    const float* wv = (const float*)d_in[3];
    const float* wo = (const float*)d_in[4];
    const float* gq = (const float*)d_in[5];
    const float* gk = (const float*)d_in[6];
    float* out = (float*)d_out;

    char* ws = (char*)d_ws;
    float*  qkv   = (float*)ws;                          // 25165824 B
    __bf16* WqkvT = (__bf16*)(ws + 25165824);            //  3145728 B
    __bf16* WoT   = (__bf16*)(ws + 28311552);            //  2097152 B
    __bf16* xb_ao = (__bf16*)(ws + 30408704);            //  8388608 B (xb, then aout)
    __bf16* Kb    = (__bf16*)(ws + 38797312);            //  2097152 B
    __bf16* Vt    = (__bf16*)(ws + 40894464);            //  2097152 B

    dim3 tb(256);
    prep_k<<<4608, tb, 0, stream>>>(wq, wk, wv, wo, x, WqkvT, WoT, xb_ao);
    gemm_bf16_k<<<dim3(32, 12), tb, 0, stream>>>(xb_ao, WqkvT, qkv, 1024, 1536);
    normv_k<<<20736, tb, 0, stream>>>(qkv, Kb, Vt, gq, gk);
    attn_k<<<dim3(128, 16, 2), dim3(64), 0, stream>>>(qkv, Kb, Vt, xb_ao);
    gemm_bf16_k<<<dim3(32, 8), tb, 0, stream>>>(xb_ao, WoT, out, 1024, 1024);
}

// Round 6
// 176.350 us; speedup vs baseline: 1.3525x; 1.2842x over previous
//
#include <hip/hip_runtime.h>
#include <hip/hip_bf16.h>

// ---------------- types ----------------
typedef __bf16 bf16x8 __attribute__((ext_vector_type(8)));
typedef __bf16 bf16x4 __attribute__((ext_vector_type(4)));
typedef float  f32x4  __attribute__((ext_vector_type(4)));
typedef short  s16x4  __attribute__((ext_vector_type(4)));

__device__ __forceinline__ __bf16 to_bf16(float f) {
    __hip_bfloat16 h = __float2bfloat16(f);
    return *reinterpret_cast<__bf16*>(&h);
}

__device__ __forceinline__ f32x4 mfma32(bf16x8 a, bf16x8 b, f32x4 c) {
    return __builtin_amdgcn_mfma_f32_16x16x32_bf16(a, b, c, 0, 0, 0);
}
// 16x16x16 bf16 MFMA (PV): S^T C-layout == B-layout, so P^T feeds directly
__device__ __forceinline__ f32x4 mfma16(bf16x4 a, bf16x4 b, f32x4 c) {
#if __has_builtin(__builtin_amdgcn_mfma_f32_16x16x16_bf16)
    return __builtin_amdgcn_mfma_f32_16x16x16_bf16(a, b, c, 0, 0, 0);
#else
    return __builtin_amdgcn_mfma_f32_16x16x16bf16_1k(
        __builtin_bit_cast(s16x4, a), __builtin_bit_cast(s16x4, b), c, 0, 0, 0);
#endif
}

// async global->LDS, 16B per lane; lds ptr must be wave-uniform (GEMM only)
__device__ __forceinline__ void gload_lds16(const __bf16* g, __bf16* l) {
    __builtin_amdgcn_global_load_lds(
        (const __attribute__((address_space(1))) void*)g,
        (__attribute__((address_space(3))) void*)l, 16, 0, 0);
}

// constants: B=2, L=2048, DIM=1024, H=16, KVH=4, HD=64, REP=4
// qkv row layout: [0,1024) q heads, [1024,1280) k heads, [1280,1536) v heads

// ---------------- fused prep: 4 weight transposes + x cast ----------------
__global__ __launch_bounds__(256) void prep_k(const float* __restrict__ wq,
                                              const float* __restrict__ wk,
                                              const float* __restrict__ wv,
                                              const float* __restrict__ wo,
                                              const float* __restrict__ x,
                                              __bf16* __restrict__ WqkvT,
                                              __bf16* __restrict__ WoT,
                                              __bf16* __restrict__ xb) {
    int b = blockIdx.x, tid = threadIdx.x;
    if (b >= 2560) {
        int i = ((b - 2560) * 256 + tid) * 8;
        f32x4 a = *(const f32x4*)(x + i);
        f32x4 c = *(const f32x4*)(x + i + 4);
        bf16x8 h;
        h[0] = to_bf16(a.x); h[1] = to_bf16(a.y); h[2] = to_bf16(a.z); h[3] = to_bf16(a.w);
        h[4] = to_bf16(c.x); h[5] = to_bf16(c.y); h[6] = to_bf16(c.z); h[7] = to_bf16(c.w);
        *(bf16x8*)(xb + i) = h;
        return;
    }
    __shared__ float tile[32][33];
    const float* src; __bf16* dst; int N, idx;
    if (b < 1024)      { src = wq; dst = WqkvT;                        N = 1024; idx = b; }
    else if (b < 1280) { src = wk; dst = WqkvT + (size_t)1024 * 1024;  N = 256;  idx = b - 1024; }
    else if (b < 1536) { src = wv; dst = WqkvT + (size_t)1280 * 1024;  N = 256;  idx = b - 1280; }
    else               { src = wo; dst = WoT;                          N = 1024; idx = b - 1536; }
    int k0 = (idx & 31) * 32, n0 = (idx >> 5) * 32;
    int tx = tid & 31, ty = tid >> 5;
#pragma unroll
    for (int r = 0; r < 4; ++r) {
        int kk = ty + r * 8;
        tile[kk][tx] = src[(size_t)(k0 + kk) * N + n0 + tx];
    }
    __syncthreads();
#pragma unroll
    for (int r = 0; r < 4; ++r) {
        int nn = ty + r * 8;
        dst[(size_t)(n0 + nn) * 1024 + k0 + tx] = to_bf16(tile[tx][nn]);
    }
}

// ---------------- GEMM (m97-style): A bf16 [M][K], BT bf16 [N][K], C f32 -------
__global__ __launch_bounds__(256) void gemm_bf16_k(const __bf16* __restrict__ A,
                                                   const __bf16* __restrict__ BT,
                                                   float* __restrict__ C,
                                                   int K, int N) {
    __shared__ __bf16 lA[128 * 32];
    __shared__ __bf16 lB[128 * 32];
    int tid = threadIdx.x;
    int m0 = blockIdx.x * 128, n0 = blockIdx.y * 128;
    int wid = tid >> 6, lane = tid & 63;
    int wm = (wid >> 1) * 64, wn = (wid & 1) * 64;
    int lm = lane & 15, qd = lane >> 4;

    f32x4 acc[4][4] = {};

    for (int k0 = 0; k0 < K; k0 += 32) {
#pragma unroll
        for (int it = 0; it < 2; ++it) {
            int c = it * 256 + tid;
            int row = c >> 2, c8 = c & 3;
            __bf16* la = lA + (it * 256 + wid * 64) * 8;
            __bf16* lb = lB + (it * 256 + wid * 64) * 8;
            gload_lds16(A  + (size_t)(m0 + row) * K + k0 + c8 * 8, la);
            gload_lds16(BT + (size_t)(n0 + row) * K + k0 + c8 * 8, lb);
        }
        __syncthreads();

        bf16x8 af[4], bfr[4];
#pragma unroll
        for (int t = 0; t < 4; ++t) {
            af[t]  = *(const bf16x8*)&lA[(wm + t * 16 + lm) * 32 + qd * 8];
            bfr[t] = *(const bf16x8*)&lB[(wn + t * 16 + lm) * 32 + qd * 8];
        }
#pragma unroll
        for (int ti = 0; ti < 4; ++ti)
#pragma unroll
            for (int tj = 0; tj < 4; ++tj)
                acc[ti][tj] = mfma32(af[ti], bfr[tj], acc[ti][tj]);
        __syncthreads();
    }

#pragma unroll
    for (int ti = 0; ti < 4; ++ti)
#pragma unroll
        for (int tj = 0; tj < 4; ++tj)
#pragma unroll
            for (int r = 0; r < 4; ++r) {
                int row = m0 + wm + ti * 16 + qd * 4 + r;
                int col = n0 + wn + tj * 16 + lm;
                C[(size_t)row * N + col] = acc[ti][tj][r];
            }
}

// ------- fused RMSNorm+RoPE (q->Qb frag layout bf16, k->Kbl bf16) + V transpose
// Qb layout: ((((g)*128 + qb)*4 + h4)*16 + ti)*64 + d   (g=b*4+kvh, 1/8 baked)
// Kbl layout: ((g)*2048 + pos)*64 + d
__global__ __launch_bounds__(256) void normv_k(const float* __restrict__ qkv,
                                               __bf16* __restrict__ Qb,
                                               __bf16* __restrict__ Kbl,
                                               __bf16* __restrict__ Vt,
                                               const float* __restrict__ gq,
                                               const float* __restrict__ gk) {
    __shared__ float tl[64][65];
    int b = blockIdx.x, tid = threadIdx.x;
    if (b < 20480) {
        int w = b * 4 + (tid >> 6);
        int lane = tid & 63;
        int t = w / 20, hs = w % 20;
        int pos = t & 2047, bb = t >> 11;
        bool isq = hs < 16;
        int col0 = isq ? hs * 64 : 1024 + (hs - 16) * 64;
        float g = isq ? gq[lane] : gk[lane];
        const float* p = qkv + (size_t)t * 1536 + col0;
        float v = p[lane];
        float ss = v * v;
#pragma unroll
        for (int o = 32; o; o >>= 1) ss += __shfl_xor(ss, o);
        float scale = rsqrtf(ss * (1.0f / 64.0f) + 1e-6f);
        v = v * scale * g;
        int i2 = lane >> 1;
        float ex = (float)(2 * i2) * (1.0f / 64.0f);
        float inv = expf(-ex * 9.210340371976184f);
        float ang = (float)pos * inv;
        float c = cosf(ang), s = sinf(ang);
        float pv = __shfl_xor(v, 1);
        float out = (lane & 1) ? (pv * s + v * c) : (v * c - pv * s);
        if (isq) {
            int kvh = hs >> 2, h4 = hs & 3;
            size_t off = (((((size_t)bb * 4 + kvh) * 128 + (pos >> 4)) * 4 + h4) * 16
                          + (pos & 15)) * 64 + lane;
            Qb[off] = to_bf16(out * 0.125f);
        } else {
            Kbl[(((size_t)bb * 4 + (hs - 16)) * 2048 + pos) * 64 + lane] = to_bf16(out);
        }
        return;
    }
    int b2 = b - 20480;
    int g = b2 >> 5, t0 = (b2 & 31) * 64;
    int bb = g >> 2, kvh = g & 3;
    int tx = tid & 63, ty = tid >> 6;
    const float* src = qkv + ((size_t)bb * 2048 + t0) * 1536 + 1280 + kvh * 64;
#pragma unroll
    for (int r = 0; r < 16; ++r) {
        int row = ty * 16 + r;
        tl[row][tx] = src[(size_t)row * 1536 + tx];
    }
    __syncthreads();
#pragma unroll
    for (int r = 0; r < 16; ++r) {
        int d = ty * 16 + r;
        Vt[((size_t)g * 64 + d) * 2048 + t0 + tx] = to_bf16(tl[tx][d]);
    }
}

// ---------------- MFMA flash attention, cooperative LDS staging ----------------
// grid (128, 4, 2): block = (qblock of 16 queries, kvh, b). 4 waves = 4 q-heads
// of the GQA group -> K/V staged ONCE per group. Double-buffered, XOR-swizzled
// LDS (16B chunks, chunk' = chunk ^ (row&7)) -> coalesced global, ~2-way max LDS.
__global__ __launch_bounds__(256) void attn_k(const __bf16* __restrict__ Qb,
                                              const __bf16* __restrict__ Kbl,
                                              const __bf16* __restrict__ Vt,
                                              __bf16* __restrict__ aout) {
    __shared__ __bf16 Kt[2][64 * 64];   // [key][dim], swizzled
    __shared__ __bf16 Vl[2][64 * 64];   // [dim][key], swizzled
    int tid = threadIdx.x, wid = tid >> 6, lane = tid & 63;
    int l15 = lane & 15, quad = lane >> 4;
    int qb = blockIdx.x, kvh = blockIdx.y, b = blockIdx.z;
    int iw = qb * 16;
    int g = b * 4 + kvh;
    int h = kvh * 4 + wid;
    int e7 = l15 & 7;

    // Q^T B-frag straight from Qb (bf16, 1/8 pre-baked)
    const __bf16* qp = Qb + ((((size_t)g * 128 + qb) * 4 + wid) * 16 + l15) * 64 + quad * 8;
    bf16x8 qf0 = *(const bf16x8*)qp;
    bf16x8 qf1 = *(const bf16x8*)(qp + 32);

    int ts = (iw - 256) >> 6; if (ts < 1) ts = 1;
    int tmax = (iw + 15) >> 6;
    int n_all = (tmax >= ts) ? (tmax - ts + 2) : 1;   // [0] ++ [ts..tmax]

    const __bf16* Kg = Kbl + (size_t)g * 2048 * 64;
    const __bf16* Vg = Vt + (size_t)g * 64 * 2048;

    // staging: 512 chunks of 8 elems; thread covers chunk tid and tid+256
    int r0 = tid >> 3, c0 = tid & 7;          // rows 0..31
    int kl0 = r0 * 64 + ((c0 ^ (r0 & 7)) * 8);
    int kl1 = kl0 + 32 * 64;                   // row+32: same (row&7), same swizzle

    bf16x8 kr0, kr1, vr0, vr1;
    auto stage_load = [&](int tt) {
        const __bf16* kb = Kg + (size_t)tt * 64 * 64;
        kr0 = *(const bf16x8*)(kb + r0 * 64 + c0 * 8);
        kr1 = *(const bf16x8*)(kb + (r0 + 32) * 64 + c0 * 8);
        const __bf16* vb = Vg + tt * 64 + c0 * 8;
        vr0 = *(const bf16x8*)(vb + (size_t)r0 * 2048);
        vr1 = *(const bf16x8*)(vb + (size_t)(r0 + 32) * 2048);
    };
    auto stage_write = [&](int buf) {
        *(bf16x8*)&Kt[buf][kl0] = kr0;
        *(bf16x8*)&Kt[buf][kl1] = kr1;
        *(bf16x8*)&Vl[buf][kl0] = vr0;
        *(bf16x8*)&Vl[buf][kl1] = vr1;
    };

    stage_load(0);
    stage_write(0);

    f32x4 o[4] = {};
    float mr = -1e30f, lrp = 0.f;
    int iq = iw + l15;

    for (int idx = 0; idx < n_all; ++idx) {
        int tt = (idx == 0) ? 0 : ts + idx - 1;
        if (idx + 1 < n_all) stage_load(ts + idx);   // next tile in flight
        __syncthreads();                              // buf[idx&1] visible
        int buf = idx & 1;

        // QK^T: S^T (C layout: row=key=nt*16+quad*4+r, col=query=l15)
        f32x4 s[4] = {};
#pragma unroll
        for (int nt = 0; nt < 4; ++nt) {
            const __bf16* kp = &Kt[buf][(nt * 16 + l15) * 64];
            bf16x8 k0 = *(const bf16x8*)(kp + ((quad ^ e7) * 8));
            bf16x8 k1 = *(const bf16x8*)(kp + (((quad + 4) ^ e7) * 8));
            s[nt] = mfma32(k0, qf0, s[nt]);
            s[nt] = mfma32(k1, qf1, s[nt]);
        }

        bool need_mask = (tt == tmax) || (tt >= 1 && tt * 64 < iw + 15 - 256);
        if (need_mask) {
#pragma unroll
            for (int nt = 0; nt < 4; ++nt)
#pragma unroll
                for (int r = 0; r < 4; ++r) {
                    int j = tt * 64 + nt * 16 + quad * 4 + r;
                    bool valid = (j <= iq) && ((j >= iq - 256) || (j < 64));
                    s[nt][r] = valid ? s[nt][r] : -1e30f;
                }
        }

        float mx = -1e30f;
#pragma unroll
        for (int nt = 0; nt < 4; ++nt)
#pragma unroll
            for (int r = 0; r < 4; ++r) mx = fmaxf(mx, s[nt][r]);
        mx = fmaxf(mx, __shfl_xor(mx, 16));
        mx = fmaxf(mx, __shfl_xor(mx, 32));
        float mn = fmaxf(mr, mx);
        float alpha = __expf(mr - mn);
        mr = mn;

        float ps = 0.f;
        bf16x4 pb[4];
#pragma unroll
        for (int nt = 0; nt < 4; ++nt)
#pragma unroll
            for (int r = 0; r < 4; ++r) {
                float pv = __expf(s[nt][r] - mn);
                ps += pv;
                pb[nt][r] = to_bf16(pv);
            }
        lrp = lrp * alpha + ps;

        // PV: A = V^T frag from LDS, B = P^T (register-direct)
#pragma unroll
        for (int dt = 0; dt < 4; ++dt) {
            o[dt] *= alpha;
            const __bf16* vp = &Vl[buf][(dt * 16 + l15) * 64];
#pragma unroll
            for (int nt = 0; nt < 4; ++nt) {
                int c8 = 2 * nt + (quad >> 1);
                bf16x4 va = *(const bf16x4*)(vp + ((c8 ^ e7) * 8) + (quad & 1) * 4);
                o[dt] = mfma16(va, pb[nt], o[dt]);
            }
        }

        if (idx + 1 < n_all) stage_write((idx + 1) & 1);
    }

    // epilogue: reduce l across quads, normalize, LDS transpose, 16B stores
    lrp += __shfl_xor(lrp, 16);
    lrp += __shfl_xor(lrp, 32);
    float inv = 1.f / lrp;
    __syncthreads();                       // done with Kt/Vl buffers
    __bf16* pr = &Kt[0][wid * 16 * 64];    // per-wave region, row=query, swizzled
#pragma unroll
    for (int dt = 0; dt < 4; ++dt)
#pragma unroll
        for (int r = 0; r < 4; ++r) {
            int e = dt * 16 + quad * 4 + r;
            int c8 = e >> 3;
            pr[l15 * 64 + ((c8 ^ e7) * 8) + (e & 7)] = to_bf16(o[dt][r] * inv);
        }
    bf16x8 o0 = *(const bf16x8*)(pr + l15 * 64 + (((2 * quad) ^ e7) * 8));
    bf16x8 o1 = *(const bf16x8*)(pr + l15 * 64 + (((2 * quad + 1) ^ e7) * 8));
    __bf16* op = aout + ((size_t)b * 2048 + iw + l15) * 1024 + h * 64 + quad * 16;
    *(bf16x8*)op = o0;
    *(bf16x8*)(op + 8) = o1;
}

// ---------------- launch ----------------
extern "C" void kernel_launch(void* const* d_in, const int* in_sizes, int n_in,
                              void* d_out, int out_size, void* d_ws, size_t ws_size,
                              hipStream_t stream) {
    const float* x  = (const float*)d_in[0];
    const float* wq = (const float*)d_in[1];
    const float* wk = (const float*)d_in[2];
    const float* wv = (const float*)d_in[3];
    const float* wo = (const float*)d_in[4];
    const float* gq = (const float*)d_in[5];
    const float* gk = (const float*)d_in[6];
    float* out = (float*)d_out;

    char* ws = (char*)d_ws;
    float*  qkv   = (float*)ws;                          // 25165824 B
    __bf16* WqkvT = (__bf16*)(ws + 25165824);            //  3145728 B
    __bf16* WoT   = (__bf16*)(ws + 28311552);            //  2097152 B
    __bf16* xb_ao = (__bf16*)(ws + 30408704);            //  8388608 B (xb, then aout)
    __bf16* Kbl   = (__bf16*)(ws + 38797312);            //  2097152 B
    __bf16* Vt    = (__bf16*)(ws + 40894464);            //  2097152 B
    __bf16* Qb    = (__bf16*)(ws + 42991616);            //  8388608 B -> total 51380224

    dim3 tb(256);
    prep_k<<<4608, tb, 0, stream>>>(wq, wk, wv, wo, x, WqkvT, WoT, xb_ao);
    gemm_bf16_k<<<dim3(32, 12), tb, 0, stream>>>(xb_ao, WqkvT, qkv, 1024, 1536);
    normv_k<<<20736, tb, 0, stream>>>(qkv, Qb, Kbl, Vt, gq, gk);
    attn_k<<<dim3(128, 4, 2), tb, 0, stream>>>(Qb, Kbl, Vt, xb_ao);   // aout reuses xb
    gemm_bf16_k<<<dim3(32, 8), tb, 0, stream>>>(xb_ao, WoT, out, 1024, 1024);
}

// Round 7
// 169.469 us; speedup vs baseline: 1.4074x; 1.0406x over previous
//
#include <hip/hip_runtime.h>
#include <hip/hip_bf16.h>

// ---------------- types ----------------
typedef __bf16 bf16x8 __attribute__((ext_vector_type(8)));
typedef __bf16 bf16x4 __attribute__((ext_vector_type(4)));
typedef float  f32x4  __attribute__((ext_vector_type(4)));
typedef short  s16x4  __attribute__((ext_vector_type(4)));

__device__ __forceinline__ __bf16 to_bf16(float f) {
    __hip_bfloat16 h = __float2bfloat16(f);
    return *reinterpret_cast<__bf16*>(&h);
}

__device__ __forceinline__ f32x4 mfma32(bf16x8 a, bf16x8 b, f32x4 c) {
    return __builtin_amdgcn_mfma_f32_16x16x32_bf16(a, b, c, 0, 0, 0);
}
// 16x16x16 bf16 MFMA (PV): S^T C-layout == B-layout, so P^T feeds directly
__device__ __forceinline__ f32x4 mfma16(bf16x4 a, bf16x4 b, f32x4 c) {
#if __has_builtin(__builtin_amdgcn_mfma_f32_16x16x16_bf16)
    return __builtin_amdgcn_mfma_f32_16x16x16_bf16(a, b, c, 0, 0, 0);
#else
    return __builtin_amdgcn_mfma_f32_16x16x16bf16_1k(
        __builtin_bit_cast(s16x4, a), __builtin_bit_cast(s16x4, b), c, 0, 0, 0);
#endif
}

// async global->LDS, 16B per lane; lds ptr must be wave-uniform (GEMM only)
__device__ __forceinline__ void gload_lds16(const __bf16* g, __bf16* l) {
    __builtin_amdgcn_global_load_lds(
        (const __attribute__((address_space(1))) void*)g,
        (__attribute__((address_space(3))) void*)l, 16, 0, 0);
}

// constants: B=2, L=2048, DIM=1024, H=16, KVH=4, HD=64, REP=4
// qkv row layout: [0,1024) q heads, [1024,1280) k heads, [1280,1536) v heads

// ---------------- fused prep: 4 weight transposes + x cast ----------------
__global__ __launch_bounds__(256) void prep_k(const float* __restrict__ wq,
                                              const float* __restrict__ wk,
                                              const float* __restrict__ wv,
                                              const float* __restrict__ wo,
                                              const float* __restrict__ x,
                                              __bf16* __restrict__ WqkvT,
                                              __bf16* __restrict__ WoT,
                                              __bf16* __restrict__ xb) {
    int b = blockIdx.x, tid = threadIdx.x;
    if (b >= 2560) {
        int i = ((b - 2560) * 256 + tid) * 8;
        f32x4 a = *(const f32x4*)(x + i);
        f32x4 c = *(const f32x4*)(x + i + 4);
        bf16x8 h;
        h[0] = to_bf16(a.x); h[1] = to_bf16(a.y); h[2] = to_bf16(a.z); h[3] = to_bf16(a.w);
        h[4] = to_bf16(c.x); h[5] = to_bf16(c.y); h[6] = to_bf16(c.z); h[7] = to_bf16(c.w);
        *(bf16x8*)(xb + i) = h;
        return;
    }
    __shared__ float tile[32][33];
    const float* src; __bf16* dst; int N, idx;
    if (b < 1024)      { src = wq; dst = WqkvT;                        N = 1024; idx = b; }
    else if (b < 1280) { src = wk; dst = WqkvT + (size_t)1024 * 1024;  N = 256;  idx = b - 1024; }
    else if (b < 1536) { src = wv; dst = WqkvT + (size_t)1280 * 1024;  N = 256;  idx = b - 1280; }
    else               { src = wo; dst = WoT;                          N = 1024; idx = b - 1536; }
    int k0 = (idx & 31) * 32, n0 = (idx >> 5) * 32;
    int tx = tid & 31, ty = tid >> 5;
#pragma unroll
    for (int r = 0; r < 4; ++r) {
        int kk = ty + r * 8;
        tile[kk][tx] = src[(size_t)(k0 + kk) * N + n0 + tx];
    }
    __syncthreads();
#pragma unroll
    for (int r = 0; r < 4; ++r) {
        int nn = ty + r * 8;
        dst[(size_t)(n0 + nn) * 1024 + k0 + tx] = to_bf16(tile[tx][nn]);
    }
}

// ------- GEMM 128x64 tile (occupancy-tuned for small grids): A[M][K], BT[N][K]
// 4 waves = 2x2 over (128 rows, 64 cols); wave tile 64x32 = 4x2 MFMAs/k-step.
// grid = (M/128)*(N/64) blocks -> 2-3 blocks/CU on our shapes (vs 1-1.5 at 128^2).
__global__ __launch_bounds__(256) void gemm_bf16_k(const __bf16* __restrict__ A,
                                                   const __bf16* __restrict__ BT,
                                                   float* __restrict__ C,
                                                   int K, int N) {
    __shared__ __bf16 lA[128 * 32];
    __shared__ __bf16 lB[64 * 32];
    int tid = threadIdx.x;
    int m0 = blockIdx.x * 128, n0 = blockIdx.y * 64;
    int wid = tid >> 6, lane = tid & 63;
    int wm = (wid & 1) * 64, wn = (wid >> 1) * 32;
    int lm = lane & 15, qd = lane >> 4;

    f32x4 acc[4][2] = {};

    for (int k0 = 0; k0 < K; k0 += 32) {
        // A: 512 chunks (2 per thread); B: 256 chunks (1 per thread)
#pragma unroll
        for (int it = 0; it < 2; ++it) {
            int c = it * 256 + tid;
            int row = c >> 2, c8 = c & 3;
            __bf16* la = lA + (it * 256 + wid * 64) * 8;   // wave-uniform base
            gload_lds16(A + (size_t)(m0 + row) * K + k0 + c8 * 8, la);
        }
        {
            int row = tid >> 2, c8 = tid & 3;
            __bf16* lb = lB + (wid * 64) * 8;
            gload_lds16(BT + (size_t)(n0 + row) * K + k0 + c8 * 8, lb);
        }
        __syncthreads();

        bf16x8 af[4], bfr[2];
#pragma unroll
        for (int t = 0; t < 4; ++t)
            af[t] = *(const bf16x8*)&lA[(wm + t * 16 + lm) * 32 + qd * 8];
#pragma unroll
        for (int j = 0; j < 2; ++j)
            bfr[j] = *(const bf16x8*)&lB[(wn + j * 16 + lm) * 32 + qd * 8];
#pragma unroll
        for (int ti = 0; ti < 4; ++ti)
#pragma unroll
            for (int tj = 0; tj < 2; ++tj)
                acc[ti][tj] = mfma32(af[ti], bfr[tj], acc[ti][tj]);
        __syncthreads();
    }

#pragma unroll
    for (int ti = 0; ti < 4; ++ti)
#pragma unroll
        for (int tj = 0; tj < 2; ++tj)
#pragma unroll
            for (int r = 0; r < 4; ++r) {
                int row = m0 + wm + ti * 16 + qd * 4 + r;
                int col = n0 + wn + tj * 16 + lm;
                C[(size_t)row * N + col] = acc[ti][tj][r];
            }
}

// ------- fused RMSNorm+RoPE (q->Qb frag layout bf16, k->Kbl bf16) + V transpose
// Qb layout: ((((g)*128 + qb)*4 + h4)*16 + ti)*64 + d   (g=b*4+kvh, 1/8 baked)
// Kbl layout: ((g)*2048 + pos)*64 + d
__global__ __launch_bounds__(256) void normv_k(const float* __restrict__ qkv,
                                               __bf16* __restrict__ Qb,
                                               __bf16* __restrict__ Kbl,
                                               __bf16* __restrict__ Vt,
                                               const float* __restrict__ gq,
                                               const float* __restrict__ gk) {
    __shared__ float tl[64][65];
    int b = blockIdx.x, tid = threadIdx.x;
    if (b < 20480) {
        int w = b * 4 + (tid >> 6);
        int lane = tid & 63;
        int t = w / 20, hs = w % 20;
        int pos = t & 2047, bb = t >> 11;
        bool isq = hs < 16;
        int col0 = isq ? hs * 64 : 1024 + (hs - 16) * 64;
        float g = isq ? gq[lane] : gk[lane];
        const float* p = qkv + (size_t)t * 1536 + col0;
        float v = p[lane];
        float ss = v * v;
#pragma unroll
        for (int o = 32; o; o >>= 1) ss += __shfl_xor(ss, o);
        float scale = rsqrtf(ss * (1.0f / 64.0f) + 1e-6f);
        v = v * scale * g;
        int i2 = lane >> 1;
        float ex = (float)(2 * i2) * (1.0f / 64.0f);
        float inv = expf(-ex * 9.210340371976184f);
        float ang = (float)pos * inv;
        float c = cosf(ang), s = sinf(ang);
        float pv = __shfl_xor(v, 1);
        float out = (lane & 1) ? (pv * s + v * c) : (v * c - pv * s);
        if (isq) {
            int kvh = hs >> 2, h4 = hs & 3;
            size_t off = (((((size_t)bb * 4 + kvh) * 128 + (pos >> 4)) * 4 + h4) * 16
                          + (pos & 15)) * 64 + lane;
            Qb[off] = to_bf16(out * 0.125f);
        } else {
            Kbl[(((size_t)bb * 4 + (hs - 16)) * 2048 + pos) * 64 + lane] = to_bf16(out);
        }
        return;
    }
    int b2 = b - 20480;
    int g = b2 >> 5, t0 = (b2 & 31) * 64;
    int bb = g >> 2, kvh = g & 3;
    int tx = tid & 63, ty = tid >> 6;
    const float* src = qkv + ((size_t)bb * 2048 + t0) * 1536 + 1280 + kvh * 64;
#pragma unroll
    for (int r = 0; r < 16; ++r) {
        int row = ty * 16 + r;
        tl[row][tx] = src[(size_t)row * 1536 + tx];
    }
    __syncthreads();
#pragma unroll
    for (int r = 0; r < 16; ++r) {
        int d = ty * 16 + r;
        Vt[((size_t)g * 64 + d) * 2048 + t0 + tx] = to_bf16(tl[tx][d]);
    }
}

// ---------------- MFMA flash attention, cooperative LDS staging ----------------
// grid (128, 4, 2): block = (qblock of 16 queries, kvh, b). 4 waves = 4 q-heads
// of the GQA group -> K/V staged ONCE per group. Double-buffered, XOR-swizzled
// LDS (16B chunks, chunk' = chunk ^ (row&7)) -> coalesced global, ~2-way max LDS.
__global__ __launch_bounds__(256) void attn_k(const __bf16* __restrict__ Qb,
                                              const __bf16* __restrict__ Kbl,
                                              const __bf16* __restrict__ Vt,
                                              __bf16* __restrict__ aout) {
    __shared__ __bf16 Kt[2][64 * 64];   // [key][dim], swizzled
    __shared__ __bf16 Vl[2][64 * 64];   // [dim][key], swizzled
    int tid = threadIdx.x, wid = tid >> 6, lane = tid & 63;
    int l15 = lane & 15, quad = lane >> 4;
    int qb = blockIdx.x, kvh = blockIdx.y, b = blockIdx.z;
    int iw = qb * 16;
    int g = b * 4 + kvh;
    int h = kvh * 4 + wid;
    int e7 = l15 & 7;

    // Q^T B-frag straight from Qb (bf16, 1/8 pre-baked)
    const __bf16* qp = Qb + ((((size_t)g * 128 + qb) * 4 + wid) * 16 + l15) * 64 + quad * 8;
    bf16x8 qf0 = *(const bf16x8*)qp;
    bf16x8 qf1 = *(const bf16x8*)(qp + 32);

    int ts = (iw - 256) >> 6; if (ts < 1) ts = 1;
    int tmax = (iw + 15) >> 6;
    int n_all = (tmax >= ts) ? (tmax - ts + 2) : 1;   // [0] ++ [ts..tmax]

    const __bf16* Kg = Kbl + (size_t)g * 2048 * 64;
    const __bf16* Vg = Vt + (size_t)g * 64 * 2048;

    // staging: 512 chunks of 8 elems; thread covers chunk tid and tid+256
    int r0 = tid >> 3, c0 = tid & 7;          // rows 0..31
    int kl0 = r0 * 64 + ((c0 ^ (r0 & 7)) * 8);
    int kl1 = kl0 + 32 * 64;                   // row+32: same (row&7), same swizzle

    bf16x8 kr0, kr1, vr0, vr1;
    auto stage_load = [&](int tt) {
        const __bf16* kb = Kg + (size_t)tt * 64 * 64;
        kr0 = *(const bf16x8*)(kb + r0 * 64 + c0 * 8);
        kr1 = *(const bf16x8*)(kb + (r0 + 32) * 64 + c0 * 8);
        const __bf16* vb = Vg + tt * 64 + c0 * 8;
        vr0 = *(const bf16x8*)(vb + (size_t)r0 * 2048);
        vr1 = *(const bf16x8*)(vb + (size_t)(r0 + 32) * 2048);
    };
    auto stage_write = [&](int buf) {
        *(bf16x8*)&Kt[buf][kl0] = kr0;
        *(bf16x8*)&Kt[buf][kl1] = kr1;
        *(bf16x8*)&Vl[buf][kl0] = vr0;
        *(bf16x8*)&Vl[buf][kl1] = vr1;
    };

    stage_load(0);
    stage_write(0);

    f32x4 o[4] = {};
    float mr = -1e30f, lrp = 0.f;
    int iq = iw + l15;

    for (int idx = 0; idx < n_all; ++idx) {
        int tt = (idx == 0) ? 0 : ts + idx - 1;
        if (idx + 1 < n_all) stage_load(ts + idx);   // next tile in flight
        __syncthreads();                              // buf[idx&1] visible
        int buf = idx & 1;

        // QK^T: S^T (C layout: row=key=nt*16+quad*4+r, col=query=l15)
        f32x4 s[4] = {};
#pragma unroll
        for (int nt = 0; nt < 4; ++nt) {
            const __bf16* kp = &Kt[buf][(nt * 16 + l15) * 64];
            bf16x8 k0 = *(const bf16x8*)(kp + ((quad ^ e7) * 8));
            bf16x8 k1 = *(const bf16x8*)(kp + (((quad + 4) ^ e7) * 8));
            s[nt] = mfma32(k0, qf0, s[nt]);
            s[nt] = mfma32(k1, qf1, s[nt]);
        }

        bool need_mask = (tt == tmax) || (tt >= 1 && tt * 64 < iw + 15 - 256);
        if (need_mask) {
#pragma unroll
            for (int nt = 0; nt < 4; ++nt)
#pragma unroll
                for (int r = 0; r < 4; ++r) {
                    int j = tt * 64 + nt * 16 + quad * 4 + r;
                    bool valid = (j <= iq) && ((j >= iq - 256) || (j < 64));
                    s[nt][r] = valid ? s[nt][r] : -1e30f;
                }
        }

        float mx = -1e30f;
#pragma unroll
        for (int nt = 0; nt < 4; ++nt)
#pragma unroll
            for (int r = 0; r < 4; ++r) mx = fmaxf(mx, s[nt][r]);
        mx = fmaxf(mx, __shfl_xor(mx, 16));
        mx = fmaxf(mx, __shfl_xor(mx, 32));
        float mn = fmaxf(mr, mx);
        float alpha = __expf(mr - mn);
        mr = mn;

        float ps = 0.f;
        bf16x4 pb[4];
#pragma unroll
        for (int nt = 0; nt < 4; ++nt)
#pragma unroll
            for (int r = 0; r < 4; ++r) {
                float pv = __expf(s[nt][r] - mn);
                ps += pv;
                pb[nt][r] = to_bf16(pv);
            }
        lrp = lrp * alpha + ps;

        // PV: A = V^T frag from LDS, B = P^T (register-direct)
#pragma unroll
        for (int dt = 0; dt < 4; ++dt) {
            o[dt] *= alpha;
            const __bf16* vp = &Vl[buf][(dt * 16 + l15) * 64];
#pragma unroll
            for (int nt = 0; nt < 4; ++nt) {
                int c8 = 2 * nt + (quad >> 1);
                bf16x4 va = *(const bf16x4*)(vp + ((c8 ^ e7) * 8) + (quad & 1) * 4);
                o[dt] = mfma16(va, pb[nt], o[dt]);
            }
        }

        if (idx + 1 < n_all) stage_write((idx + 1) & 1);
    }

    // epilogue: reduce l across quads, normalize, LDS transpose, 16B stores
    lrp += __shfl_xor(lrp, 16);
    lrp += __shfl_xor(lrp, 32);
    float inv = 1.f / lrp;
    __syncthreads();                       // done with Kt/Vl buffers
    __bf16* pr = &Kt[0][wid * 16 * 64];    // per-wave region, row=query, swizzled
#pragma unroll
    for (int dt = 0; dt < 4; ++dt)
#pragma unroll
        for (int r = 0; r < 4; ++r) {
            int e = dt * 16 + quad * 4 + r;
            int c8 = e >> 3;
            pr[l15 * 64 + ((c8 ^ e7) * 8) + (e & 7)] = to_bf16(o[dt][r] * inv);
        }
    bf16x8 o0 = *(const bf16x8*)(pr + l15 * 64 + (((2 * quad) ^ e7) * 8));
    bf16x8 o1 = *(const bf16x8*)(pr + l15 * 64 + (((2 * quad + 1) ^ e7) * 8));
    __bf16* op = aout + ((size_t)b * 2048 + iw + l15) * 1024 + h * 64 + quad * 16;
    *(bf16x8*)op = o0;
    *(bf16x8*)(op + 8) = o1;
}

// ---------------- launch ----------------
extern "C" void kernel_launch(void* const* d_in, const int* in_sizes, int n_in,
                              void* d_out, int out_size, void* d_ws, size_t ws_size,
                              hipStream_t stream) {
    const float* x  = (const float*)d_in[0];
    const float* wq = (const float*)d_in[1];
    const float* wk = (const float*)d_in[2];
    const float* wv = (const float*)d_in[3];
    const float* wo = (const float*)d_in[4];
    const float* gq = (const float*)d_in[5];
    const float* gk = (const float*)d_in[6];
    float* out = (float*)d_out;

    char* ws = (char*)d_ws;
    float*  qkv   = (float*)ws;                          // 25165824 B
    __bf16* WqkvT = (__bf16*)(ws + 25165824);            //  3145728 B
    __bf16* WoT   = (__bf16*)(ws + 28311552);            //  2097152 B
    __bf16* xb_ao = (__bf16*)(ws + 30408704);            //  8388608 B (xb, then aout)
    __bf16* Kbl   = (__bf16*)(ws + 38797312);            //  2097152 B
    __bf16* Vt    = (__bf16*)(ws + 40894464);            //  2097152 B
    __bf16* Qb    = (__bf16*)(ws + 42991616);            //  8388608 B -> total 51380224

    dim3 tb(256);
    prep_k<<<4608, tb, 0, stream>>>(wq, wk, wv, wo, x, WqkvT, WoT, xb_ao);
    gemm_bf16_k<<<dim3(32, 24), tb, 0, stream>>>(xb_ao, WqkvT, qkv, 1024, 1536);
    normv_k<<<20736, tb, 0, stream>>>(qkv, Qb, Kbl, Vt, gq, gk);
    attn_k<<<dim3(128, 4, 2), tb, 0, stream>>>(Qb, Kbl, Vt, xb_ao);   // aout reuses xb
    gemm_bf16_k<<<dim3(32, 16), tb, 0, stream>>>(xb_ao, WoT, out, 1024, 1024);
}

// Round 8
// 159.644 us; speedup vs baseline: 1.4940x; 1.0615x over previous
//
#include <hip/hip_runtime.h>
#include <hip/hip_bf16.h>

// ---------------- types ----------------
typedef __bf16 bf16x8 __attribute__((ext_vector_type(8)));
typedef __bf16 bf16x4 __attribute__((ext_vector_type(4)));
typedef float  f32x4  __attribute__((ext_vector_type(4)));
typedef short  s16x4  __attribute__((ext_vector_type(4)));

__device__ __forceinline__ __bf16 to_bf16(float f) {
    __hip_bfloat16 h = __float2bfloat16(f);
    return *reinterpret_cast<__bf16*>(&h);
}

__device__ __forceinline__ f32x4 mfma32(bf16x8 a, bf16x8 b, f32x4 c) {
    return __builtin_amdgcn_mfma_f32_16x16x32_bf16(a, b, c, 0, 0, 0);
}
// 16x16x16 bf16 MFMA (PV): S^T C-layout == B-layout, so P^T feeds directly
__device__ __forceinline__ f32x4 mfma16(bf16x4 a, bf16x4 b, f32x4 c) {
#if __has_builtin(__builtin_amdgcn_mfma_f32_16x16x16_bf16)
    return __builtin_amdgcn_mfma_f32_16x16x16_bf16(a, b, c, 0, 0, 0);
#else
    return __builtin_amdgcn_mfma_f32_16x16x16bf16_1k(
        __builtin_bit_cast(s16x4, a), __builtin_bit_cast(s16x4, b), c, 0, 0, 0);
#endif
}

// async global->LDS, 16B per lane; lds ptr must be wave-uniform (GEMM only)
__device__ __forceinline__ void gload_lds16(const __bf16* g, __bf16* l) {
    __builtin_amdgcn_global_load_lds(
        (const __attribute__((address_space(1))) void*)g,
        (__attribute__((address_space(3))) void*)l, 16, 0, 0);
}

// constants: B=2, L=2048, DIM=1024, H=16, KVH=4, HD=64, REP=4

// ---------------- fused prep: 4 weight transposes + x cast ----------------
__global__ __launch_bounds__(256) void prep_k(const float* __restrict__ wq,
                                              const float* __restrict__ wk,
                                              const float* __restrict__ wv,
                                              const float* __restrict__ wo,
                                              const float* __restrict__ x,
                                              __bf16* __restrict__ WqkvT,
                                              __bf16* __restrict__ WoT,
                                              __bf16* __restrict__ xb) {
    int b = blockIdx.x, tid = threadIdx.x;
    if (b >= 2560) {
        int i = ((b - 2560) * 256 + tid) * 8;
        f32x4 a = *(const f32x4*)(x + i);
        f32x4 c = *(const f32x4*)(x + i + 4);
        bf16x8 h;
        h[0] = to_bf16(a.x); h[1] = to_bf16(a.y); h[2] = to_bf16(a.z); h[3] = to_bf16(a.w);
        h[4] = to_bf16(c.x); h[5] = to_bf16(c.y); h[6] = to_bf16(c.z); h[7] = to_bf16(c.w);
        *(bf16x8*)(xb + i) = h;
        return;
    }
    __shared__ float tile[32][33];
    const float* src; __bf16* dst; int N, idx;
    if (b < 1024)      { src = wq; dst = WqkvT;                        N = 1024; idx = b; }
    else if (b < 1280) { src = wk; dst = WqkvT + (size_t)1024 * 1024;  N = 256;  idx = b - 1024; }
    else if (b < 1536) { src = wv; dst = WqkvT + (size_t)1280 * 1024;  N = 256;  idx = b - 1280; }
    else               { src = wo; dst = WoT;                          N = 1024; idx = b - 1536; }
    int k0 = (idx & 31) * 32, n0 = (idx >> 5) * 32;
    int tx = tid & 31, ty = tid >> 5;
#pragma unroll
    for (int r = 0; r < 4; ++r) {
        int kk = ty + r * 8;
        tile[kk][tx] = src[(size_t)(k0 + kk) * N + n0 + tx];
    }
    __syncthreads();
#pragma unroll
    for (int r = 0; r < 4; ++r) {
        int nn = ty + r * 8;
        dst[(size_t)(n0 + nn) * 1024 + k0 + tx] = to_bf16(tile[tx][nn]);
    }
}

// ------- fused QKV GEMM + RMSNorm + RoPE + layout write -------------------
// 128x64 tile; each block's 64 cols = exactly ONE head (head = n0/64).
// q heads -> Qb frag layout (1/8 baked), k heads -> Kbl, v heads -> Vt (LDS
// transpose). No fp32 qkv intermediate, no separate normv kernel.
__global__ __launch_bounds__(256) void gemmqkv_k(const __bf16* __restrict__ A,
                                                 const __bf16* __restrict__ BT,
                                                 const float* __restrict__ gq,
                                                 const float* __restrict__ gk,
                                                 __bf16* __restrict__ Qb,
                                                 __bf16* __restrict__ Kbl,
                                                 __bf16* __restrict__ Vt) {
    __shared__ __bf16 lA[128 * 32];
    __shared__ __bf16 lB[64 * 32];
    __shared__ float ssp[2][128];
    __shared__ __bf16 tv[64 * 136];      // V transpose; stride 136 (16B-aligned rows)
    const int K = 1024;
    int tid = threadIdx.x;
    int m0 = blockIdx.x * 128, n0 = blockIdx.y * 64;
    int head = n0 >> 6;
    int wid = tid >> 6, lane = tid & 63;
    int wm = (wid & 1) * 64, wn = (wid >> 1) * 32;
    int lm = lane & 15, qd = lane >> 4;

    f32x4 acc[4][2] = {};

    for (int k0 = 0; k0 < K; k0 += 32) {
#pragma unroll
        for (int it = 0; it < 2; ++it) {
            int c = it * 256 + tid;
            int row = c >> 2, c8 = c & 3;
            __bf16* la = lA + (it * 256 + wid * 64) * 8;
            gload_lds16(A + (size_t)(m0 + row) * K + k0 + c8 * 8, la);
        }
        {
            int row = tid >> 2, c8 = tid & 3;
            __bf16* lb = lB + (wid * 64) * 8;
            gload_lds16(BT + (size_t)(n0 + row) * K + k0 + c8 * 8, lb);
        }
        __syncthreads();

        bf16x8 af[4], bfr[2];
#pragma unroll
        for (int t = 0; t < 4; ++t)
            af[t] = *(const bf16x8*)&lA[(wm + t * 16 + lm) * 32 + qd * 8];
#pragma unroll
        for (int j = 0; j < 2; ++j)
            bfr[j] = *(const bf16x8*)&lB[(wn + j * 16 + lm) * 32 + qd * 8];
#pragma unroll
        for (int ti = 0; ti < 4; ++ti)
#pragma unroll
            for (int tj = 0; tj < 2; ++tj)
                acc[ti][tj] = mfma32(af[ti], bfr[tj], acc[ti][tj]);
        __syncthreads();
    }

    if (head < 20) {
        // ---- RMSNorm stats: per-row sumsq over this wave's 32 cols ----
#pragma unroll
        for (int ti = 0; ti < 4; ++ti)
#pragma unroll
            for (int r = 0; r < 4; ++r) {
                float sq = acc[ti][0][r] * acc[ti][0][r] + acc[ti][1][r] * acc[ti][1][r];
                sq += __shfl_xor(sq, 1);
                sq += __shfl_xor(sq, 2);
                sq += __shfl_xor(sq, 4);
                sq += __shfl_xor(sq, 8);
                if (lm == 0) ssp[wid >> 1][wm + ti * 16 + qd * 4 + r] = sq;
            }
        __syncthreads();

        bool isq = head < 16;
#pragma unroll
        for (int ti = 0; ti < 4; ++ti)
#pragma unroll
            for (int r = 0; r < 4; ++r) {
                int row = wm + ti * 16 + qd * 4 + r;
                int t = m0 + row;
                int pos = t & 2047, bb = t >> 11;
                float ss = ssp[0][row] + ssp[1][row];
                float scale = rsqrtf(ss * (1.0f / 64.0f) + 1e-6f);
#pragma unroll
                for (int tj = 0; tj < 2; ++tj) {
                    int col = wn + tj * 16 + lm;
                    float g = isq ? gq[col] : gk[col];
                    float v = acc[ti][tj][r] * scale * g;
                    // interleaved RoPE (pair = adjacent lm lanes)
                    float ex = (float)(2 * (col >> 1)) * (1.0f / 64.0f);
                    float invf = expf(-ex * 9.210340371976184f);
                    float ang = (float)pos * invf;
                    float c = cosf(ang), s = sinf(ang);
                    float pv = __shfl_xor(v, 1);
                    float outv = (col & 1) ? (pv * s + v * c) : (v * c - pv * s);
                    if (isq) {
                        int kvh = head >> 2, h4 = head & 3;
                        size_t off = (((((size_t)bb * 4 + kvh) * 128 + (pos >> 4)) * 4 + h4) * 16
                                      + (pos & 15)) * 64 + col;
                        Qb[off] = to_bf16(outv * 0.125f);
                    } else {
                        int kvg = head - 16;
                        Kbl[(((size_t)bb * 4 + kvg) * 2048 + pos) * 64 + col] = to_bf16(outv);
                    }
                }
            }
    } else {
        // ---- V: bf16 convert + in-block transpose, coalesced Vt rows ----
#pragma unroll
        for (int ti = 0; ti < 4; ++ti)
#pragma unroll
            for (int tj = 0; tj < 2; ++tj)
#pragma unroll
                for (int r = 0; r < 4; ++r) {
                    int row = wm + ti * 16 + qd * 4 + r;
                    int col = wn + tj * 16 + lm;
                    tv[col * 136 + row] = to_bf16(acc[ti][tj][r]);
                }
        __syncthreads();
        int bb = m0 >> 11, kvg = head - 20;
        size_t gg = (size_t)bb * 4 + kvg;
        int pos0 = m0 & 2047;
#pragma unroll
        for (int p = 0; p < 4; ++p) {
            int d = p * 16 + (tid >> 4);
            int tok = (tid & 15) * 8;
            bf16x8 vvv = *(const bf16x8*)&tv[d * 136 + tok];
            *(bf16x8*)(Vt + (gg * 64 + d) * 2048 + pos0 + tok) = vvv;
        }
    }
}

// ---------------- generic GEMM 128x64 (for output projection) ----------------
__global__ __launch_bounds__(256) void gemm_bf16_k(const __bf16* __restrict__ A,
                                                   const __bf16* __restrict__ BT,
                                                   float* __restrict__ C,
                                                   int K, int N) {
    __shared__ __bf16 lA[128 * 32];
    __shared__ __bf16 lB[64 * 32];
    int tid = threadIdx.x;
    int m0 = blockIdx.x * 128, n0 = blockIdx.y * 64;
    int wid = tid >> 6, lane = tid & 63;
    int wm = (wid & 1) * 64, wn = (wid >> 1) * 32;
    int lm = lane & 15, qd = lane >> 4;

    f32x4 acc[4][2] = {};

    for (int k0 = 0; k0 < K; k0 += 32) {
#pragma unroll
        for (int it = 0; it < 2; ++it) {
            int c = it * 256 + tid;
            int row = c >> 2, c8 = c & 3;
            __bf16* la = lA + (it * 256 + wid * 64) * 8;
            gload_lds16(A + (size_t)(m0 + row) * K + k0 + c8 * 8, la);
        }
        {
            int row = tid >> 2, c8 = tid & 3;
            __bf16* lb = lB + (wid * 64) * 8;
            gload_lds16(BT + (size_t)(n0 + row) * K + k0 + c8 * 8, lb);
        }
        __syncthreads();

        bf16x8 af[4], bfr[2];
#pragma unroll
        for (int t = 0; t < 4; ++t)
            af[t] = *(const bf16x8*)&lA[(wm + t * 16 + lm) * 32 + qd * 8];
#pragma unroll
        for (int j = 0; j < 2; ++j)
            bfr[j] = *(const bf16x8*)&lB[(wn + j * 16 + lm) * 32 + qd * 8];
#pragma unroll
        for (int ti = 0; ti < 4; ++ti)
#pragma unroll
            for (int tj = 0; tj < 2; ++tj)
                acc[ti][tj] = mfma32(af[ti], bfr[tj], acc[ti][tj]);
        __syncthreads();
    }

#pragma unroll
    for (int ti = 0; ti < 4; ++ti)
#pragma unroll
        for (int tj = 0; tj < 2; ++tj)
#pragma unroll
            for (int r = 0; r < 4; ++r) {
                int row = m0 + wm + ti * 16 + qd * 4 + r;
                int col = n0 + wn + tj * 16 + lm;
                C[(size_t)row * N + col] = acc[ti][tj][r];
            }
}

// ---------------- MFMA flash attention, cooperative LDS staging ----------------
// grid (128, 4, 2): block = (qblock of 16 queries, kvh, b). 4 waves = 4 q-heads
// of the GQA group -> K/V staged ONCE per group. Double-buffered, XOR-swizzled
// LDS (16B chunks, chunk' = chunk ^ (row&7)) -> coalesced global, ~2-way max LDS.
__global__ __launch_bounds__(256) void attn_k(const __bf16* __restrict__ Qb,
                                              const __bf16* __restrict__ Kbl,
                                              const __bf16* __restrict__ Vt,
                                              __bf16* __restrict__ aout) {
    __shared__ __bf16 Kt[2][64 * 64];   // [key][dim], swizzled
    __shared__ __bf16 Vl[2][64 * 64];   // [dim][key], swizzled
    int tid = threadIdx.x, wid = tid >> 6, lane = tid & 63;
    int l15 = lane & 15, quad = lane >> 4;
    int qb = blockIdx.x, kvh = blockIdx.y, b = blockIdx.z;
    int iw = qb * 16;
    int g = b * 4 + kvh;
    int h = kvh * 4 + wid;
    int e7 = l15 & 7;

    // Q^T B-frag straight from Qb (bf16, 1/8 pre-baked)
    const __bf16* qp = Qb + ((((size_t)g * 128 + qb) * 4 + wid) * 16 + l15) * 64 + quad * 8;
    bf16x8 qf0 = *(const bf16x8*)qp;
    bf16x8 qf1 = *(const bf16x8*)(qp + 32);

    int ts = (iw - 256) >> 6; if (ts < 1) ts = 1;
    int tmax = (iw + 15) >> 6;
    int n_all = (tmax >= ts) ? (tmax - ts + 2) : 1;   // [0] ++ [ts..tmax]

    const __bf16* Kg = Kbl + (size_t)g * 2048 * 64;
    const __bf16* Vg = Vt + (size_t)g * 64 * 2048;

    // staging: 512 chunks of 8 elems; thread covers chunk tid and tid+256
    int r0 = tid >> 3, c0 = tid & 7;          // rows 0..31
    int kl0 = r0 * 64 + ((c0 ^ (r0 & 7)) * 8);
    int kl1 = kl0 + 32 * 64;                   // row+32: same (row&7), same swizzle

    bf16x8 kr0, kr1, vr0, vr1;
    auto stage_load = [&](int tt) {
        const __bf16* kb = Kg + (size_t)tt * 64 * 64;
        kr0 = *(const bf16x8*)(kb + r0 * 64 + c0 * 8);
        kr1 = *(const bf16x8*)(kb + (r0 + 32) * 64 + c0 * 8);
        const __bf16* vb = Vg + tt * 64 + c0 * 8;
        vr0 = *(const bf16x8*)(vb + (size_t)r0 * 2048);
        vr1 = *(const bf16x8*)(vb + (size_t)(r0 + 32) * 2048);
    };
    auto stage_write = [&](int buf) {
        *(bf16x8*)&Kt[buf][kl0] = kr0;
        *(bf16x8*)&Kt[buf][kl1] = kr1;
        *(bf16x8*)&Vl[buf][kl0] = vr0;
        *(bf16x8*)&Vl[buf][kl1] = vr1;
    };

    stage_load(0);
    stage_write(0);

    f32x4 o[4] = {};
    float mr = -1e30f, lrp = 0.f;
    int iq = iw + l15;

    for (int idx = 0; idx < n_all; ++idx) {
        int tt = (idx == 0) ? 0 : ts + idx - 1;
        if (idx + 1 < n_all) stage_load(ts + idx);   // next tile in flight
        __syncthreads();                              // buf[idx&1] visible
        int buf = idx & 1;

        // QK^T: S^T (C layout: row=key=nt*16+quad*4+r, col=query=l15)
        f32x4 s[4] = {};
#pragma unroll
        for (int nt = 0; nt < 4; ++nt) {
            const __bf16* kp = &Kt[buf][(nt * 16 + l15) * 64];
            bf16x8 k0 = *(const bf16x8*)(kp + ((quad ^ e7) * 8));
            bf16x8 k1 = *(const bf16x8*)(kp + (((quad + 4) ^ e7) * 8));
            s[nt] = mfma32(k0, qf0, s[nt]);
            s[nt] = mfma32(k1, qf1, s[nt]);
        }

        bool need_mask = (tt == tmax) || (tt >= 1 && tt * 64 < iw + 15 - 256);
        if (need_mask) {
#pragma unroll
            for (int nt = 0; nt < 4; ++nt)
#pragma unroll
                for (int r = 0; r < 4; ++r) {
                    int j = tt * 64 + nt * 16 + quad * 4 + r;
                    bool valid = (j <= iq) && ((j >= iq - 256) || (j < 64));
                    s[nt][r] = valid ? s[nt][r] : -1e30f;
                }
        }

        float mx = -1e30f;
#pragma unroll
        for (int nt = 0; nt < 4; ++nt)
#pragma unroll
            for (int r = 0; r < 4; ++r) mx = fmaxf(mx, s[nt][r]);
        mx = fmaxf(mx, __shfl_xor(mx, 16));
        mx = fmaxf(mx, __shfl_xor(mx, 32));
        float mn = fmaxf(mr, mx);
        float alpha = __expf(mr - mn);
        mr = mn;

        float ps = 0.f;
        bf16x4 pb[4];
#pragma unroll
        for (int nt = 0; nt < 4; ++nt)
#pragma unroll
            for (int r = 0; r < 4; ++r) {
                float pv = __expf(s[nt][r] - mn);
                ps += pv;
                pb[nt][r] = to_bf16(pv);
            }
        lrp = lrp * alpha + ps;

        // PV: A = V^T frag from LDS, B = P^T (register-direct)
#pragma unroll
        for (int dt = 0; dt < 4; ++dt) {
            o[dt] *= alpha;
            const __bf16* vp = &Vl[buf][(dt * 16 + l15) * 64];
#pragma unroll
            for (int nt = 0; nt < 4; ++nt) {
                int c8 = 2 * nt + (quad >> 1);
                bf16x4 va = *(const bf16x4*)(vp + ((c8 ^ e7) * 8) + (quad & 1) * 4);
                o[dt] = mfma16(va, pb[nt], o[dt]);
            }
        }

        if (idx + 1 < n_all) stage_write((idx + 1) & 1);
    }

    // epilogue: reduce l across quads, normalize, LDS transpose, 16B stores
    lrp += __shfl_xor(lrp, 16);
    lrp += __shfl_xor(lrp, 32);
    float inv = 1.f / lrp;
    __syncthreads();                       // done with Kt/Vl buffers
    __bf16* pr = &Kt[0][wid * 16 * 64];    // per-wave region, row=query, swizzled
#pragma unroll
    for (int dt = 0; dt < 4; ++dt)
#pragma unroll
        for (int r = 0; r < 4; ++r) {
            int e = dt * 16 + quad * 4 + r;
            int c8 = e >> 3;
            pr[l15 * 64 + ((c8 ^ e7) * 8) + (e & 7)] = to_bf16(o[dt][r] * inv);
        }
    bf16x8 o0 = *(const bf16x8*)(pr + l15 * 64 + (((2 * quad) ^ e7) * 8));
    bf16x8 o1 = *(const bf16x8*)(pr + l15 * 64 + (((2 * quad + 1) ^ e7) * 8));
    __bf16* op = aout + ((size_t)b * 2048 + iw + l15) * 1024 + h * 64 + quad * 16;
    *(bf16x8*)op = o0;
    *(bf16x8*)(op + 8) = o1;
}

// ---------------- launch ----------------
extern "C" void kernel_launch(void* const* d_in, const int* in_sizes, int n_in,
                              void* d_out, int out_size, void* d_ws, size_t ws_size,
                              hipStream_t stream) {
    const float* x  = (const float*)d_in[0];
    const float* wq = (const float*)d_in[1];
    const float* wk = (const float*)d_in[2];
    const float* wv = (const float*)d_in[3];
    const float* wo = (const float*)d_in[4];
    const float* gq = (const float*)d_in[5];
    const float* gk = (const float*)d_in[6];
    float* out = (float*)d_out;

    char* ws = (char*)d_ws;
    __bf16* WqkvT = (__bf16*)ws;                         //  3145728 B
    __bf16* WoT   = (__bf16*)(ws + 3145728);             //  2097152 B
    __bf16* xb_ao = (__bf16*)(ws + 5242880);             //  8388608 B (xb, then aout)
    __bf16* Kbl   = (__bf16*)(ws + 13631488);            //  2097152 B
    __bf16* Vt    = (__bf16*)(ws + 15728640);            //  2097152 B
    __bf16* Qb    = (__bf16*)(ws + 17825792);            //  8388608 B -> total 26214400

    dim3 tb(256);
    prep_k<<<4608, tb, 0, stream>>>(wq, wk, wv, wo, x, WqkvT, WoT, xb_ao);
    gemmqkv_k<<<dim3(32, 24), tb, 0, stream>>>(xb_ao, WqkvT, gq, gk, Qb, Kbl, Vt);
    attn_k<<<dim3(128, 4, 2), tb, 0, stream>>>(Qb, Kbl, Vt, xb_ao);   // aout reuses xb
    gemm_bf16_k<<<dim3(32, 16), tb, 0, stream>>>(xb_ao, WoT, out, 1024, 1024);
}

// Round 9
// 149.213 us; speedup vs baseline: 1.5985x; 1.0699x over previous
//
#include <hip/hip_runtime.h>
#include <hip/hip_bf16.h>

// ---------------- types ----------------
typedef __bf16 bf16x8 __attribute__((ext_vector_type(8)));
typedef __bf16 bf16x4 __attribute__((ext_vector_type(4)));
typedef float  f32x4  __attribute__((ext_vector_type(4)));
typedef short  s16x4  __attribute__((ext_vector_type(4)));

__device__ __forceinline__ __bf16 to_bf16(float f) {
    __hip_bfloat16 h = __float2bfloat16(f);
    return *reinterpret_cast<__bf16*>(&h);
}

__device__ __forceinline__ f32x4 mfma32(bf16x8 a, bf16x8 b, f32x4 c) {
    return __builtin_amdgcn_mfma_f32_16x16x32_bf16(a, b, c, 0, 0, 0);
}
// 16x16x16 bf16 MFMA (PV): S^T C-layout == B-layout, so P^T feeds directly
__device__ __forceinline__ f32x4 mfma16(bf16x4 a, bf16x4 b, f32x4 c) {
#if __has_builtin(__builtin_amdgcn_mfma_f32_16x16x16_bf16)
    return __builtin_amdgcn_mfma_f32_16x16x16_bf16(a, b, c, 0, 0, 0);
#else
    return __builtin_amdgcn_mfma_f32_16x16x16bf16_1k(
        __builtin_bit_cast(s16x4, a), __builtin_bit_cast(s16x4, b), c, 0, 0, 0);
#endif
}

// async global->LDS, 16B per lane; lds ptr must be wave-uniform (GEMM only)
__device__ __forceinline__ void gload_lds16(const __bf16* g, __bf16* l) {
    __builtin_amdgcn_global_load_lds(
        (const __attribute__((address_space(1))) void*)g,
        (__attribute__((address_space(3))) void*)l, 16, 0, 0);
}

// constants: B=2, L=2048, DIM=1024, H=16, KVH=4, HD=64, REP=4

// ---------------- fused prep: 4 weight transposes + x cast ----------------
__global__ __launch_bounds__(256) void prep_k(const float* __restrict__ wq,
                                              const float* __restrict__ wk,
                                              const float* __restrict__ wv,
                                              const float* __restrict__ wo,
                                              const float* __restrict__ x,
                                              __bf16* __restrict__ WqkvT,
                                              __bf16* __restrict__ WoT,
                                              __bf16* __restrict__ xb) {
    int b = blockIdx.x, tid = threadIdx.x;
    if (b >= 2560) {
        int i = ((b - 2560) * 256 + tid) * 8;
        f32x4 a = *(const f32x4*)(x + i);
        f32x4 c = *(const f32x4*)(x + i + 4);
        bf16x8 h;
        h[0] = to_bf16(a.x); h[1] = to_bf16(a.y); h[2] = to_bf16(a.z); h[3] = to_bf16(a.w);
        h[4] = to_bf16(c.x); h[5] = to_bf16(c.y); h[6] = to_bf16(c.z); h[7] = to_bf16(c.w);
        *(bf16x8*)(xb + i) = h;
        return;
    }
    __shared__ float tile[32][33];
    const float* src; __bf16* dst; int N, idx;
    if (b < 1024)      { src = wq; dst = WqkvT;                        N = 1024; idx = b; }
    else if (b < 1280) { src = wk; dst = WqkvT + (size_t)1024 * 1024;  N = 256;  idx = b - 1024; }
    else if (b < 1536) { src = wv; dst = WqkvT + (size_t)1280 * 1024;  N = 256;  idx = b - 1280; }
    else               { src = wo; dst = WoT;                          N = 1024; idx = b - 1536; }
    int k0 = (idx & 31) * 32, n0 = (idx >> 5) * 32;
    int tx = tid & 31, ty = tid >> 5;
#pragma unroll
    for (int r = 0; r < 4; ++r) {
        int kk = ty + r * 8;
        tile[kk][tx] = src[(size_t)(k0 + kk) * N + n0 + tx];
    }
    __syncthreads();
#pragma unroll
    for (int r = 0; r < 4; ++r) {
        int nn = ty + r * 8;
        dst[(size_t)(n0 + nn) * 1024 + k0 + tx] = to_bf16(tile[tx][nn]);
    }
}

// ---- shared GEMM core: 128x64 tile, BK=64 (two 32-wide k-half LDS buffers;
//      stride-32 rows stay DMA-lane-linear AND bank-conflict-free) ----------
// lA: kh*4096 + (row>>6)*2048 + (row&63)*32 + col8*8   (row 0..127, 64 k-cols)
// lB: kh*2048 + row*32 + col8*8                        (row 0..63)
#define GEMM_CORE(A, BT, K)                                                     \
    __shared__ __bf16 lA[8192];                                                 \
    __shared__ __bf16 lB[4096];                                                 \
    int tid = threadIdx.x;                                                      \
    int m0 = blockIdx.x * 128, n0 = blockIdx.y * 64;                            \
    int wid = tid >> 6, lane = tid & 63;                                        \
    int wm = (wid & 1) * 64, wn = (wid >> 1) * 32;                              \
    int lm = lane & 15, qd = lane >> 4;                                         \
    f32x4 acc[4][2] = {};                                                       \
    for (int k0 = 0; k0 < (K); k0 += 64) {                                      \
        _Pragma("unroll")                                                       \
        for (int it = 0; it < 4; ++it) {                                        \
            int kh = it >> 1, half = it & 1;                                    \
            int c = half * 256 + tid;                                           \
            int row = c >> 2, c4 = c & 3;                                       \
            __bf16* la = lA + kh * 4096 + half * 2048 + wid * 512;              \
            gload_lds16((A) + (size_t)(m0 + row) * (K) + k0 + kh * 32 + c4 * 8, la); \
        }                                                                       \
        _Pragma("unroll")                                                       \
        for (int kh = 0; kh < 2; ++kh) {                                        \
            int row = tid >> 2, c4 = tid & 3;                                   \
            __bf16* lb = lB + kh * 2048 + wid * 512;                            \
            gload_lds16((BT) + (size_t)(n0 + row) * (K) + k0 + kh * 32 + c4 * 8, lb); \
        }                                                                       \
        __syncthreads();                                                        \
        _Pragma("unroll")                                                       \
        for (int kh = 0; kh < 2; ++kh) {                                        \
            bf16x8 af[4], bfr[2];                                               \
            _Pragma("unroll")                                                   \
            for (int t = 0; t < 4; ++t) {                                       \
                int row = wm + t * 16 + lm;                                     \
                af[t] = *(const bf16x8*)&lA[kh * 4096 + (row >> 6) * 2048       \
                                            + (row & 63) * 32 + qd * 8];        \
            }                                                                   \
            _Pragma("unroll")                                                   \
            for (int j = 0; j < 2; ++j)                                         \
                bfr[j] = *(const bf16x8*)&lB[kh * 2048 + (wn + j * 16 + lm) * 32 \
                                             + qd * 8];                         \
            _Pragma("unroll")                                                   \
            for (int ti = 0; ti < 4; ++ti)                                      \
                _Pragma("unroll")                                               \
                for (int tj = 0; tj < 2; ++tj)                                  \
                    acc[ti][tj] = mfma32(af[ti], bfr[tj], acc[ti][tj]);         \
        }                                                                       \
        __syncthreads();                                                        \
    }

// ------- fused QKV GEMM + RMSNorm + RoPE + layout write -------------------
__global__ __launch_bounds__(256) void gemmqkv_k(const __bf16* __restrict__ A,
                                                 const __bf16* __restrict__ BT,
                                                 const float* __restrict__ gq,
                                                 const float* __restrict__ gk,
                                                 __bf16* __restrict__ Qb,
                                                 __bf16* __restrict__ Kbl,
                                                 __bf16* __restrict__ Vt) {
    __shared__ float ssp[2][128];
    __shared__ __bf16 tv[64 * 136];
    GEMM_CORE(A, BT, 1024)
    int head = n0 >> 6;

    if (head < 20) {
#pragma unroll
        for (int ti = 0; ti < 4; ++ti)
#pragma unroll
            for (int r = 0; r < 4; ++r) {
                float sq = acc[ti][0][r] * acc[ti][0][r] + acc[ti][1][r] * acc[ti][1][r];
                sq += __shfl_xor(sq, 1);
                sq += __shfl_xor(sq, 2);
                sq += __shfl_xor(sq, 4);
                sq += __shfl_xor(sq, 8);
                if (lm == 0) ssp[wid >> 1][wm + ti * 16 + qd * 4 + r] = sq;
            }
        __syncthreads();

        bool isq = head < 16;
#pragma unroll
        for (int ti = 0; ti < 4; ++ti)
#pragma unroll
            for (int r = 0; r < 4; ++r) {
                int row = wm + ti * 16 + qd * 4 + r;
                int t = m0 + row;
                int pos = t & 2047, bb = t >> 11;
                float ss = ssp[0][row] + ssp[1][row];
                float scale = rsqrtf(ss * (1.0f / 64.0f) + 1e-6f);
#pragma unroll
                for (int tj = 0; tj < 2; ++tj) {
                    int col = wn + tj * 16 + lm;
                    float g = isq ? gq[col] : gk[col];
                    float v = acc[ti][tj][r] * scale * g;
                    float ex = (float)(2 * (col >> 1)) * (1.0f / 64.0f);
                    float invf = expf(-ex * 9.210340371976184f);
                    float ang = (float)pos * invf;
                    float c = cosf(ang), s = sinf(ang);
                    float pv = __shfl_xor(v, 1);
                    float outv = (col & 1) ? (pv * s + v * c) : (v * c - pv * s);
                    if (isq) {
                        int kvh = head >> 2, h4 = head & 3;
                        size_t off = (((((size_t)bb * 4 + kvh) * 128 + (pos >> 4)) * 4 + h4) * 16
                                      + (pos & 15)) * 64 + col;
                        Qb[off] = to_bf16(outv * 0.125f);
                    } else {
                        int kvg = head - 16;
                        Kbl[(((size_t)bb * 4 + kvg) * 2048 + pos) * 64 + col] = to_bf16(outv);
                    }
                }
            }
    } else {
#pragma unroll
        for (int ti = 0; ti < 4; ++ti)
#pragma unroll
            for (int tj = 0; tj < 2; ++tj)
#pragma unroll
                for (int r = 0; r < 4; ++r) {
                    int row = wm + ti * 16 + qd * 4 + r;
                    int col = wn + tj * 16 + lm;
                    tv[col * 136 + row] = to_bf16(acc[ti][tj][r]);
                }
        __syncthreads();
        int bb = m0 >> 11, kvg = head - 20;
        size_t gg = (size_t)bb * 4 + kvg;
        int pos0 = m0 & 2047;
#pragma unroll
        for (int p = 0; p < 4; ++p) {
            int d = p * 16 + (tid >> 4);
            int tok = (tid & 15) * 8;
            bf16x8 vvv = *(const bf16x8*)&tv[d * 136 + tok];
            *(bf16x8*)(Vt + (gg * 64 + d) * 2048 + pos0 + tok) = vvv;
        }
    }
}

// ---------------- generic GEMM 128x64 BK=64 (output projection) ---------------
__global__ __launch_bounds__(256) void gemm_bf16_k(const __bf16* __restrict__ A,
                                                   const __bf16* __restrict__ BT,
                                                   float* __restrict__ C,
                                                   int K, int N) {
    GEMM_CORE(A, BT, K)
#pragma unroll
    for (int ti = 0; ti < 4; ++ti)
#pragma unroll
        for (int tj = 0; tj < 2; ++tj)
#pragma unroll
            for (int r = 0; r < 4; ++r) {
                int row = m0 + wm + ti * 16 + qd * 4 + r;
                int col = n0 + wn + tj * 16 + lm;
                C[(size_t)row * N + col] = acc[ti][tj][r];
            }
}

// ---------------- MFMA flash attention, 32-query blocks, 8 waves ----------------
// grid (64, 4, 2): block = (32 queries, kvh, b). 8 waves = 4 heads x 2 q-groups;
// K/V staged once per 32 queries. Double-buffered XOR-swizzled LDS as before.
// Fully-masked tiles for a wave are numerically inert (alpha=1, p=0).
__global__ __launch_bounds__(512) void attn_k(const __bf16* __restrict__ Qb,
                                              const __bf16* __restrict__ Kbl,
                                              const __bf16* __restrict__ Vt,
                                              __bf16* __restrict__ aout) {
    __shared__ __bf16 Kt[2][64 * 64];   // [key][dim], swizzled
    __shared__ __bf16 Vl[2][64 * 64];   // [dim][key], swizzled
    int tid = threadIdx.x, wid = tid >> 6, lane = tid & 63;
    int l15 = lane & 15, quad = lane >> 4;
    int qb = blockIdx.x, kvh = blockIdx.y, b = blockIdx.z;
    int qg = wid >> 2;                  // query group 0/1
    int h4 = wid & 3;                   // head within group
    int iw0 = qb * 32;                  // block query base
    int iw = iw0 + qg * 16;             // wave query base
    int g = b * 4 + kvh;
    int h = kvh * 4 + h4;
    int e7 = l15 & 7;

    // Q^T B-frag straight from Qb (bf16, 1/8 pre-baked)
    int qbi = qb * 2 + qg;
    const __bf16* qp = Qb + ((((size_t)g * 128 + qbi) * 4 + h4) * 16 + l15) * 64 + quad * 8;
    bf16x8 qf0 = *(const bf16x8*)qp;
    bf16x8 qf1 = *(const bf16x8*)(qp + 32);

    int ts = (iw0 - 256) >> 6; if (ts < 1) ts = 1;
    int tmaxb = (iw0 + 31) >> 6;                       // block tile bound
    int n_all = (tmaxb >= ts) ? (tmaxb - ts + 2) : 1;  // [0] ++ [ts..tmaxb]
    int tmaxw = (iw + 15) >> 6;                        // wave mask bound

    const __bf16* Kg = Kbl + (size_t)g * 2048 * 64;
    const __bf16* Vg = Vt + (size_t)g * 64 * 2048;

    // staging: 512 threads, 1 K-chunk + 1 V-chunk of 8 elems each
    int r0 = tid >> 3, c0 = tid & 7;                   // rows 0..63
    int kl = r0 * 64 + ((c0 ^ (r0 & 7)) * 8);

    bf16x8 kr, vr;
    auto stage_load = [&](int tt) {
        kr = *(const bf16x8*)(Kg + (size_t)tt * 64 * 64 + r0 * 64 + c0 * 8);
        vr = *(const bf16x8*)(Vg + (size_t)r0 * 2048 + tt * 64 + c0 * 8);
    };
    auto stage_write = [&](int buf) {
        *(bf16x8*)&Kt[buf][kl] = kr;
        *(bf16x8*)&Vl[buf][kl] = vr;
    };

    stage_load(0);
    stage_write(0);

    f32x4 o[4] = {};
    float mr = -1e30f, lrp = 0.f;
    int iq = iw + l15;

    for (int idx = 0; idx < n_all; ++idx) {
        int tt = (idx == 0) ? 0 : ts + idx - 1;
        if (idx + 1 < n_all) stage_load(ts + idx);
        __syncthreads();
        int buf = idx & 1;

        // QK^T: S^T (C layout: row=key=nt*16+quad*4+r, col=query=l15)
        f32x4 s[4] = {};
#pragma unroll
        for (int nt = 0; nt < 4; ++nt) {
            const __bf16* kp = &Kt[buf][(nt * 16 + l15) * 64];
            bf16x8 k0 = *(const bf16x8*)(kp + ((quad ^ e7) * 8));
            bf16x8 k1 = *(const bf16x8*)(kp + (((quad + 4) ^ e7) * 8));
            s[nt] = mfma32(k0, qf0, s[nt]);
            s[nt] = mfma32(k1, qf1, s[nt]);
        }

        bool need_mask = (tt >= tmaxw) || (tt >= 1 && tt * 64 < iw + 15 - 256);
        if (need_mask) {
#pragma unroll
            for (int nt = 0; nt < 4; ++nt)
#pragma unroll
                for (int r = 0; r < 4; ++r) {
                    int j = tt * 64 + nt * 16 + quad * 4 + r;
                    bool valid = (j <= iq) && ((j >= iq - 256) || (j < 64));
                    s[nt][r] = valid ? s[nt][r] : -1e30f;
                }
        }

        float mx = -1e30f;
#pragma unroll
        for (int nt = 0; nt < 4; ++nt)
#pragma unroll
            for (int r = 0; r < 4; ++r) mx = fmaxf(mx, s[nt][r]);
        mx = fmaxf(mx, __shfl_xor(mx, 16));
        mx = fmaxf(mx, __shfl_xor(mx, 32));
        float mn = fmaxf(mr, mx);
        float alpha = __expf(mr - mn);
        mr = mn;

        float ps = 0.f;
        bf16x4 pb[4];
#pragma unroll
        for (int nt = 0; nt < 4; ++nt)
#pragma unroll
            for (int r = 0; r < 4; ++r) {
                float pv = __expf(s[nt][r] - mn);
                ps += pv;
                pb[nt][r] = to_bf16(pv);
            }
        lrp = lrp * alpha + ps;

        // PV: A = V^T frag from LDS, B = P^T (register-direct)
#pragma unroll
        for (int dt = 0; dt < 4; ++dt) {
            o[dt] *= alpha;
            const __bf16* vp = &Vl[buf][(dt * 16 + l15) * 64];
#pragma unroll
            for (int nt = 0; nt < 4; ++nt) {
                int c8 = 2 * nt + (quad >> 1);
                bf16x4 va = *(const bf16x4*)(vp + ((c8 ^ e7) * 8) + (quad & 1) * 4);
                o[dt] = mfma16(va, pb[nt], o[dt]);
            }
        }

        if (idx + 1 < n_all) stage_write((idx + 1) & 1);
    }

    // epilogue: reduce l across quads, normalize, LDS transpose, 16B stores
    lrp += __shfl_xor(lrp, 16);
    lrp += __shfl_xor(lrp, 32);
    float inv = 1.f / lrp;
    __syncthreads();                            // done with Kt/Vl buffers
    __bf16* pr = (__bf16*)Kt + wid * 16 * 64;   // 8 waves x 1024 elems = 16 KB
#pragma unroll
    for (int dt = 0; dt < 4; ++dt)
#pragma unroll
        for (int r = 0; r < 4; ++r) {
            int e = dt * 16 + quad * 4 + r;
            int c8 = e >> 3;
            pr[l15 * 64 + ((c8 ^ e7) * 8) + (e & 7)] = to_bf16(o[dt][r] * inv);
        }
    bf16x8 o0 = *(const bf16x8*)(pr + l15 * 64 + (((2 * quad) ^ e7) * 8));
    bf16x8 o1 = *(const bf16x8*)(pr + l15 * 64 + (((2 * quad + 1) ^ e7) * 8));
    __bf16* op = aout + ((size_t)b * 2048 + iw + l15) * 1024 + h * 64 + quad * 16;
    *(bf16x8*)op = o0;
    *(bf16x8*)(op + 8) = o1;
}

// ---------------- launch ----------------
extern "C" void kernel_launch(void* const* d_in, const int* in_sizes, int n_in,
                              void* d_out, int out_size, void* d_ws, size_t ws_size,
                              hipStream_t stream) {
    const float* x  = (const float*)d_in[0];
    const float* wq = (const float*)d_in[1];
    const float* wk = (const float*)d_in[2];
    const float* wv = (const float*)d_in[3];
    const float* wo = (const float*)d_in[4];
    const float* gq = (const float*)d_in[5];
    const float* gk = (const float*)d_in[6];
    float* out = (float*)d_out;

    char* ws = (char*)d_ws;
    __bf16* WqkvT = (__bf16*)ws;                         //  3145728 B
    __bf16* WoT   = (__bf16*)(ws + 3145728);             //  2097152 B
    __bf16* xb_ao = (__bf16*)(ws + 5242880);             //  8388608 B (xb, then aout)
    __bf16* Kbl   = (__bf16*)(ws + 13631488);            //  2097152 B
    __bf16* Vt    = (__bf16*)(ws + 15728640);            //  2097152 B
    __bf16* Qb    = (__bf16*)(ws + 17825792);            //  8388608 B -> total 26214400

    dim3 tb(256);
    prep_k<<<4608, tb, 0, stream>>>(wq, wk, wv, wo, x, WqkvT, WoT, xb_ao);
    gemmqkv_k<<<dim3(32, 24), tb, 0, stream>>>(xb_ao, WqkvT, gq, gk, Qb, Kbl, Vt);
    attn_k<<<dim3(64, 4, 2), dim3(512), 0, stream>>>(Qb, Kbl, Vt, xb_ao);
    gemm_bf16_k<<<dim3(32, 16), tb, 0, stream>>>(xb_ao, WoT, out, 1024, 1024);
}